// Round 15
// baseline (160.386 us; speedup 1.0000x reference)
//
#include <hip/hip_runtime.h>
#include <cstdint>
#include <cstddef>
#include <math.h>

typedef unsigned short u16;

#define S_LEN 2048
#define EMB   1024
#define HID   1024
#define NB    4

using bf16x8 = __attribute__((ext_vector_type(8))) __bf16;
using f32x4  = __attribute__((ext_vector_type(4))) float;

// ---------- helpers ----------

__device__ __forceinline__ u16 f2bf(float f) {
  union { float f; uint32_t u; } c; c.f = f;
  uint32_t u = c.u;
  uint32_t r = (u + 0x7fffu + ((u >> 16) & 1u)) >> 16;  // RNE
  return (u16)r;
}

__device__ __forceinline__ float bf2f(uint32_t hi16) {
  union { uint32_t u; float f; } c; c.u = hi16;
  return c.f;
}

__device__ __forceinline__ void gld_lds16(const u16* g, u16* l) {
  auto gp = (const __attribute__((address_space(1))) uint32_t*)(uintptr_t)(const void*)g;
  auto lp = (__attribute__((address_space(3))) uint32_t*)(uintptr_t)(void*)l;
  __builtin_amdgcn_global_load_lds(gp, lp, 16, 0, 0);
}

// ---------- fp32 -> bf16 convert: single fused launch ----------

__global__ void cvt_all(const float* __restrict__ x,  const float* __restrict__ wq,
                        const float* __restrict__ wk, const float* __restrict__ wv,
                        u16* __restrict__ xb, u16* __restrict__ wb, int nx4, int nw4lg2) {
  const int nw4 = 1 << nw4lg2;
  const int total = nx4 + 3 * nw4;
  int i = blockIdx.x * blockDim.x + threadIdx.x;
  const int stride = gridDim.x * blockDim.x;
  for (; i < total; i += stride) {
    const float* src; u16* dst; int j;
    if (i < nx4) { src = x; dst = xb; j = i; }
    else {
      const int k = i - nx4;
      const int wsel = k >> nw4lg2;
      j = k & (nw4 - 1);
      src = (wsel == 0) ? wq : (wsel == 1) ? wk : wv;
      dst = wb + ((size_t)wsel << (nw4lg2 + 2));
    }
    float4 v = reinterpret_cast<const float4*>(src)[j];
    reinterpret_cast<ushort4*>(dst)[j] =
      make_ushort4(f2bf(v.x), f2bf(v.y), f2bf(v.z), f2bf(v.w));
  }
}

// ============================================================================
// gemmT: 128x128 tile, 4 waves (2Mx2N, per-wave 64x64, acc[4][4]).
// 5-REGION LDS RING, phase = one K-half (32 cols), 32 phases (K=1024).
// Region = 16KB { A: 128r x 32k @ +0 (4096 u16), B: 128r x 32k @ +4096 }.
// LDS = 5 x 8192 u16 = 80 KB -> exactly 2 blocks/CU (160 KB).
// Phase P (R13-proven body order, deeper ring):
//   { 8 ds_read <- region (P+2)%5 (K-half P);
//     stage K-half P+3 -> region P%5 (4 gld_lds);
//     vmcnt(8); barrier; setprio(1); 16 MFMA; setprio(0) }
// vmcnt(8): steady outstanding 12 -> drains the 4 loads staged at P-2 (aged
// TWO phase-periods; the T4 lever) confirming the region read at P-1+... :
//   read at P uses region staged at P-3, confirmed by vmcnt(8)@P-1 + barrier.
// WAR: region restaged at P last read at P-2; those reads drain before
// MFMA(P-2) < reader@barrier(P-1) < writer's stage(P). One-barrier margin,
// identical to the R13-proven protocol.
// Prologue: halves 0,1,2 -> regions 2,3,4; vmcnt(0); barrier.
// Tail: stages for halves >31 clamp to 31 and land in dead regions only.
// Involution chunk swizzle (0-conflict, proven): chunk ^= row-bit3<<1 at
// global source + ds_read.
// EPI 2: bf16 out, *scale + causal mask, triangular grid (scores)
// EPI 4: fused QKV routing + bias (proj; grid 24x64 = 1536)
// ============================================================================

template<int EPI>
__global__ __launch_bounds__(256, 2)
void gemmT(const u16* __restrict__ A, const u16* __restrict__ Bw, void* __restrict__ Cv,
           const float* __restrict__ b0, const float* __restrict__ b1,
           const float* __restrict__ b2, u16* __restrict__ VT,
           int N, long sA, long sB, long sC, float scale)
{
  constexpr int K  = 1024;
  constexpr int NH = K / 32;           // 32 K-half phases
  const int z = blockIdx.z;
  A  += (long)z * sA;
  Bw += (long)z * sB;

  __shared__ __align__(16) u16 smem[40960];   // 80 KB: 5 regions x 8192 u16

  const int tid = threadIdx.x;
  const int l   = tid & 63;
  const int w   = tid >> 6;            // 0..3
  const int wr  = w >> 1;              // 0..1 (64-row)
  const int wc  = w & 1;               // 0..1 (64-col)

  int bm, bn;
  if constexpr (EPI == 2) {
    const int x0 = blockIdx.x;
    const int x  = (x0 & 7) * ((int)gridDim.x >> 3) + (x0 >> 3);
    int bi = (int)((sqrtf(8.0f * (float)x + 1.0f) - 1.0f) * 0.5f);
    while ((bi + 1) * (bi + 2) / 2 <= x) ++bi;
    while (bi * (bi + 1) / 2 > x) --bi;
    bm = bi * 128;
    bn = (x - bi * (bi + 1) / 2) * 128;
  } else {
    const int nwg = gridDim.x * gridDim.y;
    const int lin = blockIdx.y * gridDim.x + blockIdx.x;
    const int sw  = (lin & 7) * (nwg >> 3) + (lin >> 3);
    bm = (sw / gridDim.x) * 128;
    bn = (sw % gridDim.x) * 128;
  }

  // ---- staging lane geometry (pre-swizzled source chunk) ----
  // instr i covers rows i*64 + w*16 + (l>>2); chunk l&3 (8 elems = 16B);
  // source col = half*32 + swizzled_chunk*8
  const int arow = w * 16 + (l >> 2);                 // 0..63
  const int acs  = (l & 3) ^ (((l >> 5) & 1) << 1);   // chunk ^ row-bit3 flip
  const u16* gbA  = A  + (long)(bm + arow) * K + acs * 8;
  const u16* gbA2 = gbA + 64L * K;
  const u16* gbB  = Bw + (long)(bn + arow) * K + acs * 8;
  const u16* gbB2 = gbB + 64L * K;

  // stage K-half h into region base rb (u16 offset)
#define STGH(h, rb)                                                             \
  do {                                                                          \
    const long _o = (long)(h) * 32;                                             \
    gld_lds16(gbA  + _o, smem + (rb) +        w * 512);                         \
    gld_lds16(gbA2 + _o, smem + (rb) + 2048 + w * 512);                         \
    gld_lds16(gbB  + _o, smem + (rb) + 4096 +        w * 512);                  \
    gld_lds16(gbB2 + _o, smem + (rb) + 4096 + 2048 + w * 512);                  \
  } while (0)

  // ---- fragment ds_read offsets (region-local, u16 units), swizzled ----
  const int lr  = l & 15;
  const int kg  = l >> 4;
  const int kgp = kg ^ (((lr >> 3) & 1) << 1);
  int aoff[4], boff[4];
#pragma unroll
  for (int m = 0; m < 4; ++m) aoff[m] = (wr * 64 + m * 16 + lr) * 32 + kgp * 8;
#pragma unroll
  for (int n = 0; n < 4; ++n) boff[n] = 4096 + (wc * 64 + n * 16 + lr) * 32 + kgp * 8;

  f32x4 acc[4][4] = {};

  // ---- prologue: halves 0,1,2 -> regions 2,3,4; drain ----
  STGH(0, 2 * 8192);
  STGH(1, 3 * 8192);
  STGH(2, 4 * 8192);
  asm volatile("s_waitcnt vmcnt(0)" ::: "memory");
  __builtin_amdgcn_s_barrier();
  asm volatile("" ::: "memory");

  int rd = 2;   // read region for phase 0  ((0+2)%5)
  int st = 0;   // stage region for phase 0 (0%5)

#pragma unroll 1
  for (int p = 0; p < NH; ++p) {
    const int h  = (p + 3 < NH) ? p + 3 : NH - 1;   // staged K-half (clamped)
    const u16* hR = smem + rd * 8192;

    bf16x8 av[4], bv[4];
#pragma unroll
    for (int m_ = 0; m_ < 4; ++m_)
      av[m_] = *reinterpret_cast<const bf16x8*>(hR + aoff[m_]);
#pragma unroll
    for (int n_ = 0; n_ < 4; ++n_)
      bv[n_] = *reinterpret_cast<const bf16x8*>(hR + boff[n_]);

    STGH(h, st * 8192);

    asm volatile("s_waitcnt vmcnt(8)" ::: "memory");
    __builtin_amdgcn_s_barrier();
    asm volatile("" ::: "memory");

    __builtin_amdgcn_s_setprio(1);
#pragma unroll
    for (int m_ = 0; m_ < 4; ++m_)
#pragma unroll
      for (int n_ = 0; n_ < 4; ++n_)
        acc[m_][n_] = __builtin_amdgcn_mfma_f32_16x16x32_bf16(
            av[m_], bv[n_], acc[m_][n_], 0, 0, 0);
    __builtin_amdgcn_s_setprio(0);
    asm volatile("" ::: "memory");

    rd = (rd == 4) ? 0 : rd + 1;
    st = (st == 4) ? 0 : st + 1;
  }
#undef STGH

  // ---- epilogue: C map col=lane&15, row=(lane>>4)*4+q ----
  if constexpr (EPI == 2) {            // bf16, scaled, causal mask (scores)
    u16* C = (u16*)Cv + (long)z * sC;
#pragma unroll
    for (int n = 0; n < 4; ++n) {
      const int col = bn + wc * 64 + n * 16 + lr;
#pragma unroll
      for (int m = 0; m < 4; ++m) {
        const int row0 = bm + wr * 64 + m * 16 + kg * 4;
#pragma unroll
        for (int q = 0; q < 4; ++q) {
          const int row = row0 + q;
          float v = acc[m][n][q] * scale;
          if (col > row) v = -1e30f;
          C[(long)row * N + col] = f2bf(v);
        }
      }
    }
  } else {                             // EPI 4: fused QKV routing (proj)
    constexpr long M = (long)NB * S_LEN;
    const int sel = bn >> 10;          // 0=Q, 1=K, 2=V (block-uniform)
    const float* bias = (sel == 0) ? b0 : (sel == 1) ? b1 : b2;
    u16* QK = (u16*)Cv;
#pragma unroll
    for (int n = 0; n < 4; ++n) {
      const int col = bn + wc * 64 + n * 16 + lr;
      const int h   = col & (HID - 1);
      const float bbv = bias[h];
#pragma unroll
      for (int m = 0; m < 4; ++m) {
        const int row0 = bm + wr * 64 + m * 16 + kg * 4;
        if (sel < 2) {
          u16* dst = QK + (long)sel * M * HID + (long)row0 * HID + h;
#pragma unroll
          for (int q = 0; q < 4; ++q)
            dst[(long)q * HID] = f2bf(acc[m][n][q] + bbv);
        } else {
          const int b = row0 >> 11;
          const int s = row0 & (S_LEN - 1);
          ushort4 o = make_ushort4(f2bf(acc[m][n][0] + bbv), f2bf(acc[m][n][1] + bbv),
                                   f2bf(acc[m][n][2] + bbv), f2bf(acc[m][n][3] + bbv));
          *reinterpret_cast<ushort4*>(VT + ((long)b * HID + h) * S_LEN + s) = o;
        }
      }
    }
  }
}

// ============================================================================
// gemm_pv: load-balanced causal PV (R10-proven, unchanged).
// ============================================================================

__global__ __launch_bounds__(512, 2)
void gemm_pv(const u16* __restrict__ Pm, const u16* __restrict__ VTm, float* __restrict__ Cm)
{
  const int z = blockIdx.z;
  const u16* A = Pm  + (long)z * S_LEN * S_LEN;
  const u16* B = VTm + (long)z * HID * S_LEN;
  float*    Cz = Cm  + (long)z * S_LEN * HID;

  __shared__ __align__(16) u16 smem[32768];   // 64 KB

  const int tid = threadIdx.x;
  const int l   = tid & 63;
  const int w   = tid >> 6;
  const int wr  = w >> 2;              // 0..1 (64-row)
  const int wc  = w & 3;               // 0..3 (32-col)
  const int bn  = blockIdx.x * 128;
  const int pr  = blockIdx.y;          // 0..7

  const int lr  = l & 15;
  const int kg  = l >> 4;
  const int kgp = kg ^ (((lr >> 3) & 1) << 1);
  int aoff[4], boff[2];
#pragma unroll
  for (int m = 0; m < 4; ++m) aoff[m] = (wr * 64 + m * 16 + lr) * 32 + kgp * 8;
#pragma unroll
  for (int n = 0; n < 2; ++n) boff[n] = (wc * 32 + n * 16 + lr) * 32 + kgp * 8;

  const int arow = w * 16 + (l >> 2);                 // 0..127
  const int acs  = (l & 3) ^ (((l >> 5) & 1) << 1);

#pragma unroll 1
  for (int it = 0; it < 2; ++it) {
    const int bi = (it == 0) ? (15 - pr) : pr;        // long row-tile first
    const int bm = bi * 128;
    const int NTILE = (bi + 1) * 2;                   // even, >= 2

    const u16* gbA = A + (long)(bm + arow) * S_LEN + acs * 8;
    const u16* gbB = B + (long)(bn + arow) * S_LEN + acs * 8;

#define STGH(t, s, dbase)                                                       \
  do {                                                                          \
    const long _o = (long)(t) * 64 + (s) * 32;                                  \
    gld_lds16(gbA + _o, smem + (dbase) + (s) * 4096 + w * 512);                 \
    gld_lds16(gbB + _o, smem + (dbase) + 8192 + (s) * 4096 + w * 512);          \
  } while (0)

    if (it) {                          // all iter-1 LDS reads complete past here
      __builtin_amdgcn_s_barrier();
      asm volatile("" ::: "memory");
    }

    f32x4 acc[4][2] = {};

    // prologue: tile 0 both halves -> buf0; drain
    STGH(0, 0, 0);
    STGH(0, 1, 0);
    asm volatile("s_waitcnt vmcnt(0)" ::: "memory");
    __builtin_amdgcn_s_barrier();
    asm volatile("" ::: "memory");

#define PHASE(d, s, STGSTMT)                                                    \
  do {                                                                          \
    const u16* hA = smem + (d) * 16384 + (s) * 4096;                            \
    const u16* hB = smem + (d) * 16384 + 8192 + (s) * 4096;                     \
    bf16x8 av[4], bv[2];                                                        \
    _Pragma("unroll")                                                           \
    for (int m_ = 0; m_ < 4; ++m_)                                              \
      av[m_] = *reinterpret_cast<const bf16x8*>(hA + aoff[m_]);                 \
    _Pragma("unroll")                                                           \
    for (int n_ = 0; n_ < 2; ++n_)                                              \
      bv[n_] = *reinterpret_cast<const bf16x8*>(hB + boff[n_]);                 \
    STGSTMT;                                                                    \
    asm volatile("s_waitcnt vmcnt(2)" ::: "memory");                            \
    __builtin_amdgcn_s_barrier();                                               \
    asm volatile("" ::: "memory");                                              \
    __builtin_amdgcn_s_setprio(1);                                              \
    _Pragma("unroll")                                                           \
    for (int m_ = 0; m_ < 4; ++m_)                                              \
      _Pragma("unroll")                                                         \
      for (int n_ = 0; n_ < 2; ++n_)                                            \
        acc[m_][n_] = __builtin_amdgcn_mfma_f32_16x16x32_bf16(                  \
            av[m_], bv[n_], acc[m_][n_], 0, 0, 0);                              \
    __builtin_amdgcn_s_setprio(0);                                              \
    asm volatile("" ::: "memory");                                              \
  } while (0)

#pragma unroll 1
    for (int i = 0; i < NTILE / 2; ++i) {
      const int t1 = 2 * i + 1;
      const int t2 = (2 * i + 2 < NTILE) ? 2 * i + 2 : NTILE - 1;
      PHASE(0, 0, STGH(t1, 0, 16384));
      PHASE(0, 1, STGH(t1, 1, 16384));
      PHASE(1, 0, STGH(t2, 0, 0));
      PHASE(1, 1, STGH(t2, 1, 0));
    }
#undef PHASE
#undef STGH

    // epilogue: C map col=lane&15, row=(lane>>4)*4+q
#pragma unroll
    for (int n = 0; n < 2; ++n) {
      const int col = bn + wc * 32 + n * 16 + lr;
#pragma unroll
      for (int m = 0; m < 4; ++m) {
        const int row0 = bm + wr * 64 + m * 16 + kg * 4;
#pragma unroll
        for (int q = 0; q < 4; ++q)
          Cz[(long)(row0 + q) * HID + col] = acc[m][n][q];
      }
    }
  }
}

// ---------- causal row softmax: bf16 scores -> bf16 P (kend 128-aligned) ----------

__global__ __launch_bounds__(256)
void softmax_causal(const u16* __restrict__ Sc, u16* __restrict__ P, long sS, long sP)
{
  const int row  = blockIdx.x;
  const int z    = blockIdx.y;
  const int kend = ((row >> 7) + 1) << 7;
  const u16* srow = Sc + (long)z * sS + (long)row * S_LEN;
  u16*      prow = P  + (long)z * sP + (long)row * S_LEN;
  const int t = threadIdx.x;
  const int lane = t & 63, wave = t >> 6;

  const bool p0 = (8 * t) < kend;

  float e[8];
  float mx = -1e30f;
  if (p0) {
    uint4 u = reinterpret_cast<const uint4*>(srow)[t];
    uint32_t wv[4] = {u.x, u.y, u.z, u.w};
#pragma unroll
    for (int i = 0; i < 4; ++i) {
      const float lo = bf2f((wv[i] & 0xffffu) << 16);
      const float hi = bf2f(wv[i] & 0xffff0000u);
      e[2 * i]     = lo;
      e[2 * i + 1] = hi;
      mx = fmaxf(mx, fmaxf(lo, hi));
    }
  }

  __shared__ float red[8];
#pragma unroll
  for (int off = 32; off; off >>= 1) mx = fmaxf(mx, __shfl_down(mx, off));
  if (lane == 0) red[wave] = mx;
  __syncthreads();
  mx = fmaxf(fmaxf(red[0], red[1]), fmaxf(red[2], red[3]));

  float sm = 0.0f;
  if (p0) {
#pragma unroll
    for (int i = 0; i < 8; ++i) e[i] = __expf(e[i] - mx);
    sm = ((e[0] + e[1]) + (e[2] + e[3])) + ((e[4] + e[5]) + (e[6] + e[7]));
  }
#pragma unroll
  for (int off = 32; off; off >>= 1) sm += __shfl_down(sm, off);
  if (lane == 0) red[4 + wave] = sm;
  __syncthreads();
  sm = (red[4] + red[5]) + (red[6] + red[7]);

  const float inv = 1.0f / sm;
  if (p0) {
    uint32_t o[4];
#pragma unroll
    for (int i = 0; i < 4; ++i) {
      const uint32_t a = f2bf(e[2 * i] * inv);
      const uint32_t b = f2bf(e[2 * i + 1] * inv);
      o[i] = a | (b << 16);
    }
    reinterpret_cast<uint4*>(prow)[t] = make_uint4(o[0], o[1], o[2], o[3]);
  }
}

// ---------- launch ----------

extern "C" void kernel_launch(void* const* d_in, const int* in_sizes, int n_in,
                              void* d_out, int out_size, void* d_ws, size_t ws_size,
                              hipStream_t stream)
{
  const float* x  = (const float*)d_in[0];
  const float* Wq = (const float*)d_in[1];
  const float* bq = (const float*)d_in[2];
  const float* Wk = (const float*)d_in[3];
  const float* bk = (const float*)d_in[4];
  const float* Wv = (const float*)d_in[5];
  const float* bv = (const float*)d_in[6];
  float* out = (float*)d_out;

  const long M = (long)NB * S_LEN;  // 8192

  u16* xb  = (u16*)d_ws;
  u16* wqb = xb  + M * EMB;         // wq/wk/wv contiguous -> fused [3072,1024]
  u16* Qb  = wqb + 3L * HID * EMB;  // Q then K contiguous
  u16* Kb  = Qb  + M * HID;
  u16* VT  = Kb  + M * HID;
  char* rest = (char*)(VT + M * HID);
  const size_t used  = (size_t)(rest - (char*)d_ws);
  const size_t ssz   = (size_t)S_LEN * S_LEN;
  const size_t need4 = used + (size_t)NB * ssz * 2 * 2;   // bf16 scores + bf16 P
  const int nb = (ws_size >= need4) ? NB : 1;
  u16* scores = (u16*)rest;
  u16* P      = scores + (size_t)nb * ssz;

  // fp32 -> bf16 (single fused launch; nw4 = 1024*1024/4 = 2^18)
  cvt_all<<<2048, 256, 0, stream>>>(x, Wq, Wk, Wv, xb, wqb, (int)(M * EMB / 4), 18);

  // fused QKV projection: 128x128 4-wave 5-region template, grid 1536
  gemmT<4><<<dim3(24, 64, 1), 256, 0, stream>>>(xb, wqb, Qb, bq, bk, bv, VT,
                                                3 * HID, 0, 0, 0, 1.0f);

  const float scale = 0.03125f;  // 1/sqrt(1024)
  const int TRI = 16 * 17 / 2;   // 136 lower-tri 128x128 blocks

  if (nb == NB) {
    dim3 gs(TRI, 1, NB);
    gemmT<2><<<gs, 256, 0, stream>>>(Qb, Kb, scores, nullptr, nullptr, nullptr, nullptr,
                                     S_LEN, (long)S_LEN * HID, (long)S_LEN * HID,
                                     (long)ssz, scale);
    softmax_causal<<<dim3(S_LEN, NB), 256, 0, stream>>>(scores, P, (long)ssz, (long)ssz);
    gemm_pv<<<dim3(8, 8, NB), 512, 0, stream>>>(P, VT, out);
  } else {
    for (int b = 0; b < NB; ++b) {
      const u16* Qbb = Qb + (long)b * S_LEN * HID;
      const u16* Kbb = Kb + (long)b * S_LEN * HID;
      const u16* VTb = VT + (long)b * HID * S_LEN;
      float* outb = out + (long)b * S_LEN * HID;
      dim3 gs(TRI, 1, 1);
      gemmT<2><<<gs, 256, 0, stream>>>(Qbb, Kbb, scores, nullptr, nullptr, nullptr, nullptr,
                                       S_LEN, 0, 0, 0, scale);
      softmax_causal<<<dim3(S_LEN, 1), 256, 0, stream>>>(scores, P, 0, 0);
      gemm_pv<<<dim3(8, 8, 1), 512, 0, stream>>>(P, VTb, outb);
    }
  }
}

// Round 16
// 155.819 us; speedup vs baseline: 1.0293x; 1.0293x over previous
//
#include <hip/hip_runtime.h>
#include <cstdint>
#include <cstddef>
#include <math.h>

typedef unsigned short u16;

#define S_LEN 2048
#define EMB   1024
#define HID   1024
#define NB    4

using bf16x8 = __attribute__((ext_vector_type(8))) __bf16;
using f32x4  = __attribute__((ext_vector_type(4))) float;

// ---------- helpers ----------

__device__ __forceinline__ u16 f2bf(float f) {
  union { float f; uint32_t u; } c; c.f = f;
  uint32_t u = c.u;
  uint32_t r = (u + 0x7fffu + ((u >> 16) & 1u)) >> 16;  // RNE
  return (u16)r;
}

__device__ __forceinline__ float bf2f(uint32_t hi16) {
  union { uint32_t u; float f; } c; c.u = hi16;
  return c.f;
}

__device__ __forceinline__ void gld_lds16(const u16* g, u16* l) {
  auto gp = (const __attribute__((address_space(1))) uint32_t*)(uintptr_t)(const void*)g;
  auto lp = (__attribute__((address_space(3))) uint32_t*)(uintptr_t)(void*)l;
  __builtin_amdgcn_global_load_lds(gp, lp, 16, 0, 0);
}

// ---------- fp32 -> bf16 convert: single fused launch ----------

__global__ void cvt_all(const float* __restrict__ x,  const float* __restrict__ wq,
                        const float* __restrict__ wk, const float* __restrict__ wv,
                        u16* __restrict__ xb, u16* __restrict__ wb, int nx4, int nw4lg2) {
  const int nw4 = 1 << nw4lg2;
  const int total = nx4 + 3 * nw4;
  int i = blockIdx.x * blockDim.x + threadIdx.x;
  const int stride = gridDim.x * blockDim.x;
  for (; i < total; i += stride) {
    const float* src; u16* dst; int j;
    if (i < nx4) { src = x; dst = xb; j = i; }
    else {
      const int k = i - nx4;
      const int wsel = k >> nw4lg2;
      j = k & (nw4 - 1);
      src = (wsel == 0) ? wq : (wsel == 1) ? wk : wv;
      dst = wb + ((size_t)wsel << (nw4lg2 + 2));
    }
    float4 v = reinterpret_cast<const float4*>(src)[j];
    reinterpret_cast<ushort4*>(dst)[j] =
      make_ushort4(f2bf(v.x), f2bf(v.y), f2bf(v.z), f2bf(v.w));
  }
}

// ============================================================================
// gemm_proj8: fused QKV projection at the m201 operating point.
// Tile 128x256, K=1024; 512 thr = 8 waves (2M x 4N -> per-wave 64x64,
// acc[4][4], 16 MFMA/phase); 1 block/CU (96 KB LDS); grid 256 = exact fill;
// 3 sequential tiles per block (768 tiles total).
// LDS: 4-region ring x 12288 u16 (24 KB): { A:128rx32k @+0 (4096), B:256rx32k
// @+4096 (8192) }. Phase p (R13-proven 1-barrier protocol, re-ledgered):
//   { 8 ds_read <- region p&3 (K-half p);
//     if p+2 < 32: stage K-half p+2 -> region (p+2)&3 (3 gld_lds);
//     vmcnt(3) [or vmcnt(0) for p >= 30]; barrier; setprio; 16 MFMA; setprio }
// Ledger: reads at p use region staged at p-2, confirmed by vmcnt@p-1 (drains
// p-2's 3 loads; outstanding 6->3) + barrier(p-1). WAR: region restaged at p
// was read at p-2; reads drain before MFMA(p-2) < barrier(p-1) < stage(p).
// Tail (p=30,31): no stage, vmcnt(0) -> zero outstanding at tile end -> no
// WAW with next tile's prologue. Inter-tile barrier protects last reads.
// Prologue: half0->r0, half1->r1 (6 loads); vmcnt(3) [half0 landed]; barrier.
// Involution chunk swizzle (0-conflict proven): chunk ^= row-bit3<<1 at
// global source + ds_read.
// Epilogue: QKV routing + bias (sel wave-uniform; Q/K row-major, V transposed)
// ============================================================================

__global__ __launch_bounds__(512, 1)
void gemm_proj8(const u16* __restrict__ A, const u16* __restrict__ Bw, u16* __restrict__ QK,
                const float* __restrict__ b0, const float* __restrict__ b1,
                const float* __restrict__ b2, u16* __restrict__ VT)
{
  constexpr int K  = 1024;
  constexpr int NH = K / 32;            // 32 K-half phases per tile
  constexpr long M = (long)NB * S_LEN;  // 8192

  __shared__ __align__(16) u16 smem[49152];   // 96 KB: 4 regions x 12288 u16

  const int tid = threadIdx.x;
  const int l   = tid & 63;
  const int w   = tid >> 6;            // 0..7
  const int wr  = w >> 2;              // 0..1 (64-row)
  const int wc  = w & 3;               // 0..3 (64-col)

  // fragment ds_read offsets (region-local, u16 units), swizzled
  const int lr  = l & 15;
  const int kg  = l >> 4;
  const int kgp = kg ^ (((lr >> 3) & 1) << 1);
  int aoff[4], boff[4];
#pragma unroll
  for (int m = 0; m < 4; ++m) aoff[m] = (wr * 64 + m * 16 + lr) * 32 + kgp * 8;
#pragma unroll
  for (int n = 0; n < 4; ++n) boff[n] = 4096 + (wc * 64 + n * 16 + lr) * 32 + kgp * 8;

  // staging lane geometry: row = tid>>2 (0..127), chunk = (tid&3) ^ row-bit3 flip
  const int srow = tid >> 2;
  const int acs  = (tid & 3) ^ (((tid >> 5) & 1) << 1);

#pragma unroll 1
  for (int t = 0; t < 3; ++t) {
    const int g  = blockIdx.x + t * 256;     // 0..767
    const int bm = (g & 63) * 128;
    const int bn = (g >> 6) * 256;

    const u16* gbA  = A  + (long)(bm + srow) * K + acs * 8;
    const u16* gbB  = Bw + (long)(bn + srow) * K + acs * 8;
    const u16* gbB2 = gbB + 128L * K;

    // stage K-half h into region base rb (u16 offset): A 1 instr + B 2 instr
#define STGH(h, rb)                                                             \
  do {                                                                          \
    const long _o = (long)(h) * 32;                                             \
    gld_lds16(gbA  + _o, smem + (rb) +              w * 512);                   \
    gld_lds16(gbB  + _o, smem + (rb) + 4096 +       w * 512);                   \
    gld_lds16(gbB2 + _o, smem + (rb) + 4096 + 4096 + w * 512);                  \
  } while (0)

    if (t) {                         // protect last tile's LDS reads
      __builtin_amdgcn_s_barrier();
      asm volatile("" ::: "memory");
    }

    f32x4 acc[4][4] = {};

    // prologue: half0 -> r0, half1 -> r1; confirm half0
    STGH(0, 0);
    STGH(1, 12288);
    asm volatile("s_waitcnt vmcnt(3)" ::: "memory");
    __builtin_amdgcn_s_barrier();
    asm volatile("" ::: "memory");

#pragma unroll 1
    for (int p = 0; p < NH; ++p) {
      const u16* hR = smem + (p & 3) * 12288;

      bf16x8 av[4], bv[4];
#pragma unroll
      for (int m_ = 0; m_ < 4; ++m_)
        av[m_] = *reinterpret_cast<const bf16x8*>(hR + aoff[m_]);
#pragma unroll
      for (int n_ = 0; n_ < 4; ++n_)
        bv[n_] = *reinterpret_cast<const bf16x8*>(hR + boff[n_]);

      if (p + 2 < NH) {
        const int rb = ((p + 2) & 3) * 12288;
        STGH(p + 2, rb);
        asm volatile("s_waitcnt vmcnt(3)" ::: "memory");
      } else {
        asm volatile("s_waitcnt vmcnt(0)" ::: "memory");
      }
      __builtin_amdgcn_s_barrier();
      asm volatile("" ::: "memory");

      __builtin_amdgcn_s_setprio(1);
#pragma unroll
      for (int m_ = 0; m_ < 4; ++m_)
#pragma unroll
        for (int n_ = 0; n_ < 4; ++n_)
          acc[m_][n_] = __builtin_amdgcn_mfma_f32_16x16x32_bf16(
              av[m_], bv[n_], acc[m_][n_], 0, 0, 0);
      __builtin_amdgcn_s_setprio(0);
      asm volatile("" ::: "memory");
    }
#undef STGH

    // epilogue: C map col=lane&15, row=(lane>>4)*4+q
    const int sel = (bn + wc * 64) >> 10;   // 0=Q,1=K,2=V (wave-uniform)
    const float* bias = (sel == 0) ? b0 : (sel == 1) ? b1 : b2;
#pragma unroll
    for (int n = 0; n < 4; ++n) {
      const int col = bn + wc * 64 + n * 16 + lr;
      const int h   = col & (HID - 1);
      const float bbv = bias[h];
#pragma unroll
      for (int m = 0; m < 4; ++m) {
        const int row0 = bm + wr * 64 + m * 16 + kg * 4;
        if (sel < 2) {
          u16* dst = QK + (long)sel * M * HID + (long)row0 * HID + h;
#pragma unroll
          for (int q = 0; q < 4; ++q)
            dst[(long)q * HID] = f2bf(acc[m][n][q] + bbv);
        } else {
          const int b = row0 >> 11;
          const int s = row0 & (S_LEN - 1);
          ushort4 o = make_ushort4(f2bf(acc[m][n][0] + bbv), f2bf(acc[m][n][1] + bbv),
                                   f2bf(acc[m][n][2] + bbv), f2bf(acc[m][n][3] + bbv));
          *reinterpret_cast<ushort4*>(VT + ((long)b * HID + h) * S_LEN + s) = o;
        }
      }
    }
  }
}

// ============================================================================
// gemmT: scores GEMM (R13-proven, unchanged): 128x128, 256 thr, 4 waves,
// 4-region protocol, bf16 out + scale + causal mask, triangular grid.
// ============================================================================

__global__ __launch_bounds__(256, 2)
void gemmT(const u16* __restrict__ A, const u16* __restrict__ Bw, void* __restrict__ Cv,
           int N, long sA, long sB, long sC, float scale)
{
  constexpr int K = 1024;
  constexpr int NTILE = K / 64;        // 16
  const int z = blockIdx.z;
  A  += (long)z * sA;
  Bw += (long)z * sB;

  __shared__ __align__(16) u16 smem[32768];   // 64 KB

  const int tid = threadIdx.x;
  const int l   = tid & 63;
  const int w   = tid >> 6;            // 0..3
  const int wr  = w >> 1;              // 0..1
  const int wc  = w & 1;               // 0..1

  const int x0 = blockIdx.x;
  const int x  = (x0 & 7) * ((int)gridDim.x >> 3) + (x0 >> 3);
  int bi = (int)((sqrtf(8.0f * (float)x + 1.0f) - 1.0f) * 0.5f);
  while ((bi + 1) * (bi + 2) / 2 <= x) ++bi;
  while (bi * (bi + 1) / 2 > x) --bi;
  const int bm = bi * 128;
  const int bn = (x - bi * (bi + 1) / 2) * 128;

  const int arow = w * 16 + (l >> 2);                 // 0..63
  const int acs  = (l & 3) ^ (((l >> 5) & 1) << 1);
  const u16* gbA  = A  + (long)(bm + arow) * K + acs * 8;
  const u16* gbA2 = gbA + 64L * K;
  const u16* gbB  = Bw + (long)(bn + arow) * K + acs * 8;
  const u16* gbB2 = gbB + 64L * K;

#define STGH(t, s, dbase)                                                       \
  do {                                                                          \
    const long _o = (long)(t) * 64 + (s) * 32;                                  \
    gld_lds16(gbA  + _o, smem + (dbase) + (s) * 4096 +        w * 512);         \
    gld_lds16(gbA2 + _o, smem + (dbase) + (s) * 4096 + 2048 + w * 512);         \
    gld_lds16(gbB  + _o, smem + (dbase) + 8192 + (s) * 4096 +        w * 512);  \
    gld_lds16(gbB2 + _o, smem + (dbase) + 8192 + (s) * 4096 + 2048 + w * 512);  \
  } while (0)

  const int lr  = l & 15;
  const int kg  = l >> 4;
  const int kgp = kg ^ (((lr >> 3) & 1) << 1);
  int aoff[4], boff[4];
#pragma unroll
  for (int m = 0; m < 4; ++m) aoff[m] = (wr * 64 + m * 16 + lr) * 32 + kgp * 8;
#pragma unroll
  for (int n = 0; n < 4; ++n) boff[n] = (wc * 64 + n * 16 + lr) * 32 + kgp * 8;

  f32x4 acc[4][4] = {};

  STGH(0, 0, 0);
  STGH(0, 1, 0);
  asm volatile("s_waitcnt vmcnt(0)" ::: "memory");
  __builtin_amdgcn_s_barrier();
  asm volatile("" ::: "memory");

#define PHASE(d, s, STGSTMT)                                                    \
  do {                                                                          \
    const u16* hA = smem + (d) * 16384 + (s) * 4096;                            \
    const u16* hB = smem + (d) * 16384 + 8192 + (s) * 4096;                     \
    bf16x8 av[4], bv[4];                                                        \
    _Pragma("unroll")                                                           \
    for (int m_ = 0; m_ < 4; ++m_)                                              \
      av[m_] = *reinterpret_cast<const bf16x8*>(hA + aoff[m_]);                 \
    _Pragma("unroll")                                                           \
    for (int n_ = 0; n_ < 4; ++n_)                                              \
      bv[n_] = *reinterpret_cast<const bf16x8*>(hB + boff[n_]);                 \
    STGSTMT;                                                                    \
    asm volatile("s_waitcnt vmcnt(4)" ::: "memory");                            \
    __builtin_amdgcn_s_barrier();                                               \
    asm volatile("" ::: "memory");                                              \
    __builtin_amdgcn_s_setprio(1);                                              \
    _Pragma("unroll")                                                           \
    for (int m_ = 0; m_ < 4; ++m_)                                              \
      _Pragma("unroll")                                                         \
      for (int n_ = 0; n_ < 4; ++n_)                                            \
        acc[m_][n_] = __builtin_amdgcn_mfma_f32_16x16x32_bf16(                  \
            av[m_], bv[n_], acc[m_][n_], 0, 0, 0);                              \
    __builtin_amdgcn_s_setprio(0);                                              \
    asm volatile("" ::: "memory");                                              \
  } while (0)

#pragma unroll 1
  for (int i = 0; i < NTILE / 2; ++i) {
    const int t1 = 2 * i + 1;
    const int t2 = (2 * i + 2 < NTILE) ? 2 * i + 2 : NTILE - 1;
    PHASE(0, 0, STGH(t1, 0, 16384));
    PHASE(0, 1, STGH(t1, 1, 16384));
    PHASE(1, 0, STGH(t2, 0, 0));
    PHASE(1, 1, STGH(t2, 1, 0));
  }
#undef PHASE
#undef STGH

  u16* C = (u16*)Cv + (long)z * sC;
#pragma unroll
  for (int n = 0; n < 4; ++n) {
    const int col = bn + wc * 64 + n * 16 + lr;
#pragma unroll
    for (int m = 0; m < 4; ++m) {
      const int row0 = bm + wr * 64 + m * 16 + kg * 4;
#pragma unroll
      for (int q = 0; q < 4; ++q) {
        const int row = row0 + q;
        float v = acc[m][n][q] * scale;
        if (col > row) v = -1e30f;
        C[(long)row * N + col] = f2bf(v);
      }
    }
  }
}

// ============================================================================
// gemm_pv: load-balanced causal PV (R10-proven, unchanged).
// ============================================================================

__global__ __launch_bounds__(512, 2)
void gemm_pv(const u16* __restrict__ Pm, const u16* __restrict__ VTm, float* __restrict__ Cm)
{
  const int z = blockIdx.z;
  const u16* A = Pm  + (long)z * S_LEN * S_LEN;
  const u16* B = VTm + (long)z * HID * S_LEN;
  float*    Cz = Cm  + (long)z * S_LEN * HID;

  __shared__ __align__(16) u16 smem[32768];   // 64 KB

  const int tid = threadIdx.x;
  const int l   = tid & 63;
  const int w   = tid >> 6;
  const int wr  = w >> 2;              // 0..1 (64-row)
  const int wc  = w & 3;               // 0..3 (32-col)
  const int bn  = blockIdx.x * 128;
  const int pr  = blockIdx.y;          // 0..7

  const int lr  = l & 15;
  const int kg  = l >> 4;
  const int kgp = kg ^ (((lr >> 3) & 1) << 1);
  int aoff[4], boff[2];
#pragma unroll
  for (int m = 0; m < 4; ++m) aoff[m] = (wr * 64 + m * 16 + lr) * 32 + kgp * 8;
#pragma unroll
  for (int n = 0; n < 2; ++n) boff[n] = (wc * 32 + n * 16 + lr) * 32 + kgp * 8;

  const int arow = w * 16 + (l >> 2);                 // 0..127
  const int acs  = (l & 3) ^ (((l >> 5) & 1) << 1);

#pragma unroll 1
  for (int it = 0; it < 2; ++it) {
    const int bi = (it == 0) ? (15 - pr) : pr;        // long row-tile first
    const int bm = bi * 128;
    const int NTILE = (bi + 1) * 2;                   // even, >= 2

    const u16* gbA = A + (long)(bm + arow) * S_LEN + acs * 8;
    const u16* gbB = B + (long)(bn + arow) * S_LEN + acs * 8;

#define STGH(t, s, dbase)                                                       \
  do {                                                                          \
    const long _o = (long)(t) * 64 + (s) * 32;                                  \
    gld_lds16(gbA + _o, smem + (dbase) + (s) * 4096 + w * 512);                 \
    gld_lds16(gbB + _o, smem + (dbase) + 8192 + (s) * 4096 + w * 512);          \
  } while (0)

    if (it) {
      __builtin_amdgcn_s_barrier();
      asm volatile("" ::: "memory");
    }

    f32x4 acc[4][2] = {};

    STGH(0, 0, 0);
    STGH(0, 1, 0);
    asm volatile("s_waitcnt vmcnt(0)" ::: "memory");
    __builtin_amdgcn_s_barrier();
    asm volatile("" ::: "memory");

#define PHASE(d, s, STGSTMT)                                                    \
  do {                                                                          \
    const u16* hA = smem + (d) * 16384 + (s) * 4096;                            \
    const u16* hB = smem + (d) * 16384 + 8192 + (s) * 4096;                     \
    bf16x8 av[4], bv[2];                                                        \
    _Pragma("unroll")                                                           \
    for (int m_ = 0; m_ < 4; ++m_)                                              \
      av[m_] = *reinterpret_cast<const bf16x8*>(hA + aoff[m_]);                 \
    _Pragma("unroll")                                                           \
    for (int n_ = 0; n_ < 2; ++n_)                                              \
      bv[n_] = *reinterpret_cast<const bf16x8*>(hB + boff[n_]);                 \
    STGSTMT;                                                                    \
    asm volatile("s_waitcnt vmcnt(2)" ::: "memory");                            \
    __builtin_amdgcn_s_barrier();                                               \
    asm volatile("" ::: "memory");                                              \
    __builtin_amdgcn_s_setprio(1);                                              \
    _Pragma("unroll")                                                           \
    for (int m_ = 0; m_ < 4; ++m_)                                              \
      _Pragma("unroll")                                                         \
      for (int n_ = 0; n_ < 2; ++n_)                                            \
        acc[m_][n_] = __builtin_amdgcn_mfma_f32_16x16x32_bf16(                  \
            av[m_], bv[n_], acc[m_][n_], 0, 0, 0);                              \
    __builtin_amdgcn_s_setprio(0);                                              \
    asm volatile("" ::: "memory");                                              \
  } while (0)

#pragma unroll 1
    for (int i = 0; i < NTILE / 2; ++i) {
      const int t1 = 2 * i + 1;
      const int t2 = (2 * i + 2 < NTILE) ? 2 * i + 2 : NTILE - 1;
      PHASE(0, 0, STGH(t1, 0, 16384));
      PHASE(0, 1, STGH(t1, 1, 16384));
      PHASE(1, 0, STGH(t2, 0, 0));
      PHASE(1, 1, STGH(t2, 1, 0));
    }
#undef PHASE
#undef STGH

#pragma unroll
    for (int n = 0; n < 2; ++n) {
      const int col = bn + wc * 32 + n * 16 + lr;
#pragma unroll
      for (int m = 0; m < 4; ++m) {
        const int row0 = bm + wr * 64 + m * 16 + kg * 4;
#pragma unroll
        for (int q = 0; q < 4; ++q)
          Cz[(long)(row0 + q) * HID + col] = acc[m][n][q];
      }
    }
  }
}

// ---------- causal row softmax: bf16 scores -> bf16 P (kend 128-aligned) ----------

__global__ __launch_bounds__(256)
void softmax_causal(const u16* __restrict__ Sc, u16* __restrict__ P, long sS, long sP)
{
  const int row  = blockIdx.x;
  const int z    = blockIdx.y;
  const int kend = ((row >> 7) + 1) << 7;
  const u16* srow = Sc + (long)z * sS + (long)row * S_LEN;
  u16*      prow = P  + (long)z * sP + (long)row * S_LEN;
  const int t = threadIdx.x;
  const int lane = t & 63, wave = t >> 6;

  const bool p0 = (8 * t) < kend;

  float e[8];
  float mx = -1e30f;
  if (p0) {
    uint4 u = reinterpret_cast<const uint4*>(srow)[t];
    uint32_t wv[4] = {u.x, u.y, u.z, u.w};
#pragma unroll
    for (int i = 0; i < 4; ++i) {
      const float lo = bf2f((wv[i] & 0xffffu) << 16);
      const float hi = bf2f(wv[i] & 0xffff0000u);
      e[2 * i]     = lo;
      e[2 * i + 1] = hi;
      mx = fmaxf(mx, fmaxf(lo, hi));
    }
  }

  __shared__ float red[8];
#pragma unroll
  for (int off = 32; off; off >>= 1) mx = fmaxf(mx, __shfl_down(mx, off));
  if (lane == 0) red[wave] = mx;
  __syncthreads();
  mx = fmaxf(fmaxf(red[0], red[1]), fmaxf(red[2], red[3]));

  float sm = 0.0f;
  if (p0) {
#pragma unroll
    for (int i = 0; i < 8; ++i) e[i] = __expf(e[i] - mx);
    sm = ((e[0] + e[1]) + (e[2] + e[3])) + ((e[4] + e[5]) + (e[6] + e[7]));
  }
#pragma unroll
  for (int off = 32; off; off >>= 1) sm += __shfl_down(sm, off);
  if (lane == 0) red[4 + wave] = sm;
  __syncthreads();
  sm = (red[4] + red[5]) + (red[6] + red[7]);

  const float inv = 1.0f / sm;
  if (p0) {
    uint32_t o[4];
#pragma unroll
    for (int i = 0; i < 4; ++i) {
      const uint32_t a = f2bf(e[2 * i] * inv);
      const uint32_t b = f2bf(e[2 * i + 1] * inv);
      o[i] = a | (b << 16);
    }
    reinterpret_cast<uint4*>(prow)[t] = make_uint4(o[0], o[1], o[2], o[3]);
  }
}

// ---------- launch ----------

extern "C" void kernel_launch(void* const* d_in, const int* in_sizes, int n_in,
                              void* d_out, int out_size, void* d_ws, size_t ws_size,
                              hipStream_t stream)
{
  const float* x  = (const float*)d_in[0];
  const float* Wq = (const float*)d_in[1];
  const float* bq = (const float*)d_in[2];
  const float* Wk = (const float*)d_in[3];
  const float* bk = (const float*)d_in[4];
  const float* Wv = (const float*)d_in[5];
  const float* bv = (const float*)d_in[6];
  float* out = (float*)d_out;

  const long M = (long)NB * S_LEN;  // 8192

  u16* xb  = (u16*)d_ws;
  u16* wqb = xb  + M * EMB;         // wq/wk/wv contiguous -> fused [3072,1024]
  u16* Qb  = wqb + 3L * HID * EMB;  // Q then K contiguous
  u16* Kb  = Qb  + M * HID;
  u16* VT  = Kb  + M * HID;
  char* rest = (char*)(VT + M * HID);
  const size_t used  = (size_t)(rest - (char*)d_ws);
  const size_t ssz   = (size_t)S_LEN * S_LEN;
  const size_t need4 = used + (size_t)NB * ssz * 2 * 2;   // bf16 scores + bf16 P
  const int nb = (ws_size >= need4) ? NB : 1;
  u16* scores = (u16*)rest;
  u16* P      = scores + (size_t)nb * ssz;

  // fp32 -> bf16 (single fused launch; nw4 = 1024*1024/4 = 2^18)
  cvt_all<<<2048, 256, 0, stream>>>(x, Wq, Wk, Wv, xb, wqb, (int)(M * EMB / 4), 18);

  // fused QKV projection: 128x256 @ 1 block/CU, 3 sequential tiles, grid 256
  gemm_proj8<<<256, 512, 0, stream>>>(xb, wqb, Qb, bq, bk, bv, VT);

  const float scale = 0.03125f;  // 1/sqrt(1024)
  const int TRI = 16 * 17 / 2;   // 136 lower-tri 128x128 blocks

  if (nb == NB) {
    dim3 gs(TRI, 1, NB);
    gemmT<<<gs, 256, 0, stream>>>(Qb, Kb, scores,
                                  S_LEN, (long)S_LEN * HID, (long)S_LEN * HID,
                                  (long)ssz, scale);
    softmax_causal<<<dim3(S_LEN, NB), 256, 0, stream>>>(scores, P, (long)ssz, (long)ssz);
    gemm_pv<<<dim3(8, 8, NB), 512, 0, stream>>>(P, VT, out);
  } else {
    for (int b = 0; b < NB; ++b) {
      const u16* Qbb = Qb + (long)b * S_LEN * HID;
      const u16* Kbb = Kb + (long)b * S_LEN * HID;
      const u16* VTb = VT + (long)b * HID * S_LEN;
      float* outb = out + (long)b * S_LEN * HID;
      dim3 gs(TRI, 1, 1);
      gemmT<<<gs, 256, 0, stream>>>(Qbb, Kbb, scores, S_LEN, 0, 0, 0, scale);
      softmax_causal<<<dim3(S_LEN, 1), 256, 0, stream>>>(scores, P, 0, 0);
      gemm_pv<<<dim3(8, 8, 1), 512, 0, stream>>>(P, VTb, outb);
    }
  }
}

// Round 17
// 153.074 us; speedup vs baseline: 1.0478x; 1.0179x over previous
//
#include <hip/hip_runtime.h>
#include <cstdint>
#include <cstddef>
#include <math.h>

typedef unsigned short u16;

#define S_LEN 2048
#define EMB   1024
#define HID   1024
#define NB    4

using bf16x8 = __attribute__((ext_vector_type(8))) __bf16;
using f32x4  = __attribute__((ext_vector_type(4))) float;

// ---------- helpers ----------

__device__ __forceinline__ u16 f2bf(float f) {
  union { float f; uint32_t u; } c; c.f = f;
  uint32_t u = c.u;
  uint32_t r = (u + 0x7fffu + ((u >> 16) & 1u)) >> 16;  // RNE
  return (u16)r;
}

__device__ __forceinline__ float bf2f(uint32_t hi16) {
  union { uint32_t u; float f; } c; c.u = hi16;
  return c.f;
}

__device__ __forceinline__ void gld_lds16(const u16* g, u16* l) {
  auto gp = (const __attribute__((address_space(1))) uint32_t*)(uintptr_t)(const void*)g;
  auto lp = (__attribute__((address_space(3))) uint32_t*)(uintptr_t)(void*)l;
  __builtin_amdgcn_global_load_lds(gp, lp, 16, 0, 0);
}

// ---------- fp32 -> bf16 convert: single fused launch ----------

__global__ void cvt_all(const float* __restrict__ x,  const float* __restrict__ wq,
                        const float* __restrict__ wk, const float* __restrict__ wv,
                        u16* __restrict__ xb, u16* __restrict__ wb, int nx4, int nw4lg2) {
  const int nw4 = 1 << nw4lg2;
  const int total = nx4 + 3 * nw4;
  int i = blockIdx.x * blockDim.x + threadIdx.x;
  const int stride = gridDim.x * blockDim.x;
  for (; i < total; i += stride) {
    const float* src; u16* dst; int j;
    if (i < nx4) { src = x; dst = xb; j = i; }
    else {
      const int k = i - nx4;
      const int wsel = k >> nw4lg2;
      j = k & (nw4 - 1);
      src = (wsel == 0) ? wq : (wsel == 1) ? wk : wv;
      dst = wb + ((size_t)wsel << (nw4lg2 + 2));
    }
    float4 v = reinterpret_cast<const float4*>(src)[j];
    reinterpret_cast<ushort4*>(dst)[j] =
      make_ushort4(f2bf(v.x), f2bf(v.y), f2bf(v.z), f2bf(v.w));
  }
}

// ============================================================================
// gemm_proj8: fused QKV projection, CONTINUOUS 4-region ring across 3 tiles.
// Tile 128x256, K=1024; 512 thr = 8 waves (2M x 4N, per-wave 64x64, acc[4][4],
// 16 MFMA/phase); 96 KB LDS; grid 256 = 1 block/CU exact; 96 global phases.
// Region = 24KB { A:128rx32k @+0 (4096 u16), B:256rx32k @+4096 (8192 u16) }.
// Phase p (local, tile t; global gp = t*32+p; region = p&3 since 32%4==0):
//   { 8 ds_read <- region p&3;
//     stage: p<30 -> half p+2 of tile t; p>=30 & t<2 -> half p-30 of tile t+1
//            (same target region (p+2)&3); t==2 & p>=30 -> none;
//     vmcnt(3) [vmcnt(0) for t==2, p>=30]; barrier; setprio; 16 MFMA; setprio }
// Ledger (R16-proven, extended across tiles): half at region r read at p was
// staged at gp-2 and drained by vmcnt(3)@gp-1 + barrier. WAR at the tile
// boundary: region restaged at gp was last read at gp-2; those reads complete
// before MFMA(gp-2) < barrier(gp-1) release < stage(gp). Epilogue (regs +
// global stores only) sits between barrier(31) and the next phase's barrier —
// no LDS hazard. Single prologue (halves 0,1 of tile 0); single tail drain.
// Outer t-loop fully unrolled -> tile base pointers compile-time (rule #20).
// Involution chunk swizzle (0-conflict proven): chunk ^= row-bit3<<1.
// Epilogue: QKV routing + bias (sel wave-uniform; Q/K row-major, V transposed)
// ============================================================================

__global__ __launch_bounds__(512, 1)
void gemm_proj8(const u16* __restrict__ A, const u16* __restrict__ Bw, u16* __restrict__ QK,
                const float* __restrict__ b0, const float* __restrict__ b1,
                const float* __restrict__ b2, u16* __restrict__ VT)
{
  constexpr int K  = 1024;
  constexpr long M = (long)NB * S_LEN;  // 8192

  __shared__ __align__(16) u16 smem[49152];   // 96 KB: 4 regions x 12288 u16

  const int tid = threadIdx.x;
  const int l   = tid & 63;
  const int w   = tid >> 6;            // 0..7
  const int wr  = w >> 2;              // 0..1 (64-row)
  const int wc  = w & 3;               // 0..3 (64-col)

  // fragment ds_read offsets (region-local, u16 units), swizzled
  const int lr  = l & 15;
  const int kg  = l >> 4;
  const int kgp = kg ^ (((lr >> 3) & 1) << 1);
  int aoff[4], boff[4];
#pragma unroll
  for (int m = 0; m < 4; ++m) aoff[m] = (wr * 64 + m * 16 + lr) * 32 + kgp * 8;
#pragma unroll
  for (int n = 0; n < 4; ++n) boff[n] = 4096 + (wc * 64 + n * 16 + lr) * 32 + kgp * 8;

  // staging lane geometry: row = tid>>2 (0..127), chunk = (tid&3) ^ row-bit3 flip
  const int srow = tid >> 2;
  const int acs  = (tid & 3) ^ (((tid >> 5) & 1) << 1);

  // per-tile geometry (compile-time indexed via unrolled outer loop)
  int bms[3], bns[3];
  const u16 *bA[3], *bB[3], *bB2[3];
#pragma unroll
  for (int t = 0; t < 3; ++t) {
    const int g = blockIdx.x + t * 256;      // 0..767
    bms[t] = (g & 63) * 128;
    bns[t] = (g >> 6) * 256;
    bA[t]  = A  + (long)(bms[t] + srow) * K + acs * 8;
    bB[t]  = Bw + (long)(bns[t] + srow) * K + acs * 8;
    bB2[t] = bB[t] + 128L * K;
  }

  // stage K-half h of tile tt into region rb (u16 offset)
#define STGH(tt, h, rb)                                                         \
  do {                                                                          \
    const long _o = (long)(h) * 32;                                             \
    gld_lds16(bA[tt]  + _o, smem + (rb) +        w * 512);                      \
    gld_lds16(bB[tt]  + _o, smem + (rb) + 4096 + w * 512);                      \
    gld_lds16(bB2[tt] + _o, smem + (rb) + 8192 + w * 512);                      \
  } while (0)

  // ---- single prologue: halves 0,1 of tile 0 -> regions 0,1 ----
  STGH(0, 0, 0);
  STGH(0, 1, 12288);
  asm volatile("s_waitcnt vmcnt(3)" ::: "memory");   // half 0 landed
  __builtin_amdgcn_s_barrier();
  asm volatile("" ::: "memory");

#pragma unroll
  for (int t = 0; t < 3; ++t) {
    f32x4 acc[4][4] = {};

#pragma unroll 1
    for (int p = 0; p < 32; ++p) {
      const u16* hR = smem + (p & 3) * 12288;

      bf16x8 av[4], bv[4];
#pragma unroll
      for (int m_ = 0; m_ < 4; ++m_)
        av[m_] = *reinterpret_cast<const bf16x8*>(hR + aoff[m_]);
#pragma unroll
      for (int n_ = 0; n_ < 4; ++n_)
        bv[n_] = *reinterpret_cast<const bf16x8*>(hR + boff[n_]);

      const int rb = ((p + 2) & 3) * 12288;
      if (p < 30) {
        STGH(t, p + 2, rb);
        asm volatile("s_waitcnt vmcnt(3)" ::: "memory");
      } else if (t < 2) {
        STGH(t + 1, p - 30, rb);                 // next tile's halves 0,1
        asm volatile("s_waitcnt vmcnt(3)" ::: "memory");
      } else {
        asm volatile("s_waitcnt vmcnt(0)" ::: "memory");
      }
      __builtin_amdgcn_s_barrier();
      asm volatile("" ::: "memory");

      __builtin_amdgcn_s_setprio(1);
#pragma unroll
      for (int m_ = 0; m_ < 4; ++m_)
#pragma unroll
        for (int n_ = 0; n_ < 4; ++n_)
          acc[m_][n_] = __builtin_amdgcn_mfma_f32_16x16x32_bf16(
              av[m_], bv[n_], acc[m_][n_], 0, 0, 0);
      __builtin_amdgcn_s_setprio(0);
      asm volatile("" ::: "memory");
    }

    // ---- epilogue tile t (regs + global stores only; no LDS) ----
    const int bm = bms[t], bn = bns[t];
    const int sel = (bn + wc * 64) >> 10;   // 0=Q,1=K,2=V (wave-uniform)
    const float* bias = (sel == 0) ? b0 : (sel == 1) ? b1 : b2;
#pragma unroll
    for (int n = 0; n < 4; ++n) {
      const int col = bn + wc * 64 + n * 16 + lr;
      const int h   = col & (HID - 1);
      const float bbv = bias[h];
#pragma unroll
      for (int m = 0; m < 4; ++m) {
        const int row0 = bm + wr * 64 + m * 16 + kg * 4;
        if (sel < 2) {
          u16* dst = QK + (long)sel * M * HID + (long)row0 * HID + h;
#pragma unroll
          for (int q = 0; q < 4; ++q)
            dst[(long)q * HID] = f2bf(acc[m][n][q] + bbv);
        } else {
          const int b = row0 >> 11;
          const int s = row0 & (S_LEN - 1);
          ushort4 o = make_ushort4(f2bf(acc[m][n][0] + bbv), f2bf(acc[m][n][1] + bbv),
                                   f2bf(acc[m][n][2] + bbv), f2bf(acc[m][n][3] + bbv));
          *reinterpret_cast<ushort4*>(VT + ((long)b * HID + h) * S_LEN + s) = o;
        }
      }
    }
  }
#undef STGH
}

// ============================================================================
// gemmT: scores GEMM (R13-proven, unchanged): 128x128, 256 thr, 4 waves,
// bf16 out + scale + causal mask, triangular grid + T1 swizzle.
// ============================================================================

__global__ __launch_bounds__(256, 2)
void gemmT(const u16* __restrict__ A, const u16* __restrict__ Bw, void* __restrict__ Cv,
           int N, long sA, long sB, long sC, float scale)
{
  constexpr int K = 1024;
  constexpr int NTILE = K / 64;        // 16
  const int z = blockIdx.z;
  A  += (long)z * sA;
  Bw += (long)z * sB;

  __shared__ __align__(16) u16 smem[32768];   // 64 KB

  const int tid = threadIdx.x;
  const int l   = tid & 63;
  const int w   = tid >> 6;            // 0..3
  const int wr  = w >> 1;              // 0..1
  const int wc  = w & 1;               // 0..1

  const int x0 = blockIdx.x;
  const int x  = (x0 & 7) * ((int)gridDim.x >> 3) + (x0 >> 3);
  int bi = (int)((sqrtf(8.0f * (float)x + 1.0f) - 1.0f) * 0.5f);
  while ((bi + 1) * (bi + 2) / 2 <= x) ++bi;
  while (bi * (bi + 1) / 2 > x) --bi;
  const int bm = bi * 128;
  const int bn = (x - bi * (bi + 1) / 2) * 128;

  const int arow = w * 16 + (l >> 2);                 // 0..63
  const int acs  = (l & 3) ^ (((l >> 5) & 1) << 1);
  const u16* gbA  = A  + (long)(bm + arow) * K + acs * 8;
  const u16* gbA2 = gbA + 64L * K;
  const u16* gbB  = Bw + (long)(bn + arow) * K + acs * 8;
  const u16* gbB2 = gbB + 64L * K;

#define STGH(t, s, dbase)                                                       \
  do {                                                                          \
    const long _o = (long)(t) * 64 + (s) * 32;                                  \
    gld_lds16(gbA  + _o, smem + (dbase) + (s) * 4096 +        w * 512);         \
    gld_lds16(gbA2 + _o, smem + (dbase) + (s) * 4096 + 2048 + w * 512);         \
    gld_lds16(gbB  + _o, smem + (dbase) + 8192 + (s) * 4096 +        w * 512);  \
    gld_lds16(gbB2 + _o, smem + (dbase) + 8192 + (s) * 4096 + 2048 + w * 512);  \
  } while (0)

  const int lr  = l & 15;
  const int kg  = l >> 4;
  const int kgp = kg ^ (((lr >> 3) & 1) << 1);
  int aoff[4], boff[4];
#pragma unroll
  for (int m = 0; m < 4; ++m) aoff[m] = (wr * 64 + m * 16 + lr) * 32 + kgp * 8;
#pragma unroll
  for (int n = 0; n < 4; ++n) boff[n] = (wc * 64 + n * 16 + lr) * 32 + kgp * 8;

  f32x4 acc[4][4] = {};

  STGH(0, 0, 0);
  STGH(0, 1, 0);
  asm volatile("s_waitcnt vmcnt(0)" ::: "memory");
  __builtin_amdgcn_s_barrier();
  asm volatile("" ::: "memory");

#define PHASE(d, s, STGSTMT)                                                    \
  do {                                                                          \
    const u16* hA = smem + (d) * 16384 + (s) * 4096;                            \
    const u16* hB = smem + (d) * 16384 + 8192 + (s) * 4096;                     \
    bf16x8 av[4], bv[4];                                                        \
    _Pragma("unroll")                                                           \
    for (int m_ = 0; m_ < 4; ++m_)                                              \
      av[m_] = *reinterpret_cast<const bf16x8*>(hA + aoff[m_]);                 \
    _Pragma("unroll")                                                           \
    for (int n_ = 0; n_ < 4; ++n_)                                              \
      bv[n_] = *reinterpret_cast<const bf16x8*>(hB + boff[n_]);                 \
    STGSTMT;                                                                    \
    asm volatile("s_waitcnt vmcnt(4)" ::: "memory");                            \
    __builtin_amdgcn_s_barrier();                                               \
    asm volatile("" ::: "memory");                                              \
    __builtin_amdgcn_s_setprio(1);                                              \
    _Pragma("unroll")                                                           \
    for (int m_ = 0; m_ < 4; ++m_)                                              \
      _Pragma("unroll")                                                         \
      for (int n_ = 0; n_ < 4; ++n_)                                            \
        acc[m_][n_] = __builtin_amdgcn_mfma_f32_16x16x32_bf16(                  \
            av[m_], bv[n_], acc[m_][n_], 0, 0, 0);                              \
    __builtin_amdgcn_s_setprio(0);                                              \
    asm volatile("" ::: "memory");                                              \
  } while (0)

#pragma unroll 1
  for (int i = 0; i < NTILE / 2; ++i) {
    const int t1 = 2 * i + 1;
    const int t2 = (2 * i + 2 < NTILE) ? 2 * i + 2 : NTILE - 1;
    PHASE(0, 0, STGH(t1, 0, 16384));
    PHASE(0, 1, STGH(t1, 1, 16384));
    PHASE(1, 0, STGH(t2, 0, 0));
    PHASE(1, 1, STGH(t2, 1, 0));
  }
#undef PHASE
#undef STGH

  u16* C = (u16*)Cv + (long)z * sC;
#pragma unroll
  for (int n = 0; n < 4; ++n) {
    const int col = bn + wc * 64 + n * 16 + lr;
#pragma unroll
    for (int m = 0; m < 4; ++m) {
      const int row0 = bm + wr * 64 + m * 16 + kg * 4;
#pragma unroll
      for (int q = 0; q < 4; ++q) {
        const int row = row0 + q;
        float v = acc[m][n][q] * scale;
        if (col > row) v = -1e30f;
        C[(long)row * N + col] = f2bf(v);
      }
    }
  }
}

// ============================================================================
// gemm_pv: load-balanced causal PV (R10-proven, unchanged).
// ============================================================================

__global__ __launch_bounds__(512, 2)
void gemm_pv(const u16* __restrict__ Pm, const u16* __restrict__ VTm, float* __restrict__ Cm)
{
  const int z = blockIdx.z;
  const u16* A = Pm  + (long)z * S_LEN * S_LEN;
  const u16* B = VTm + (long)z * HID * S_LEN;
  float*    Cz = Cm  + (long)z * S_LEN * HID;

  __shared__ __align__(16) u16 smem[32768];   // 64 KB

  const int tid = threadIdx.x;
  const int l   = tid & 63;
  const int w   = tid >> 6;
  const int wr  = w >> 2;              // 0..1 (64-row)
  const int wc  = w & 3;               // 0..3 (32-col)
  const int bn  = blockIdx.x * 128;
  const int pr  = blockIdx.y;          // 0..7

  const int lr  = l & 15;
  const int kg  = l >> 4;
  const int kgp = kg ^ (((lr >> 3) & 1) << 1);
  int aoff[4], boff[2];
#pragma unroll
  for (int m = 0; m < 4; ++m) aoff[m] = (wr * 64 + m * 16 + lr) * 32 + kgp * 8;
#pragma unroll
  for (int n = 0; n < 2; ++n) boff[n] = (wc * 32 + n * 16 + lr) * 32 + kgp * 8;

  const int arow = w * 16 + (l >> 2);                 // 0..127
  const int acs  = (l & 3) ^ (((l >> 5) & 1) << 1);

#pragma unroll 1
  for (int it = 0; it < 2; ++it) {
    const int bi = (it == 0) ? (15 - pr) : pr;        // long row-tile first
    const int bm = bi * 128;
    const int NTILE = (bi + 1) * 2;                   // even, >= 2

    const u16* gbA = A + (long)(bm + arow) * S_LEN + acs * 8;
    const u16* gbB = B + (long)(bn + arow) * S_LEN + acs * 8;

#define STGH(t, s, dbase)                                                       \
  do {                                                                          \
    const long _o = (long)(t) * 64 + (s) * 32;                                  \
    gld_lds16(gbA + _o, smem + (dbase) + (s) * 4096 + w * 512);                 \
    gld_lds16(gbB + _o, smem + (dbase) + 8192 + (s) * 4096 + w * 512);          \
  } while (0)

    if (it) {
      __builtin_amdgcn_s_barrier();
      asm volatile("" ::: "memory");
    }

    f32x4 acc[4][2] = {};

    STGH(0, 0, 0);
    STGH(0, 1, 0);
    asm volatile("s_waitcnt vmcnt(0)" ::: "memory");
    __builtin_amdgcn_s_barrier();
    asm volatile("" ::: "memory");

#define PHASE(d, s, STGSTMT)                                                    \
  do {                                                                          \
    const u16* hA = smem + (d) * 16384 + (s) * 4096;                            \
    const u16* hB = smem + (d) * 16384 + 8192 + (s) * 4096;                     \
    bf16x8 av[4], bv[2];                                                        \
    _Pragma("unroll")                                                           \
    for (int m_ = 0; m_ < 4; ++m_)                                              \
      av[m_] = *reinterpret_cast<const bf16x8*>(hA + aoff[m_]);                 \
    _Pragma("unroll")                                                           \
    for (int n_ = 0; n_ < 2; ++n_)                                              \
      bv[n_] = *reinterpret_cast<const bf16x8*>(hB + boff[n_]);                 \
    STGSTMT;                                                                    \
    asm volatile("s_waitcnt vmcnt(2)" ::: "memory");                            \
    __builtin_amdgcn_s_barrier();                                               \
    asm volatile("" ::: "memory");                                              \
    __builtin_amdgcn_s_setprio(1);                                              \
    _Pragma("unroll")                                                           \
    for (int m_ = 0; m_ < 4; ++m_)                                              \
      _Pragma("unroll")                                                         \
      for (int n_ = 0; n_ < 2; ++n_)                                            \
        acc[m_][n_] = __builtin_amdgcn_mfma_f32_16x16x32_bf16(                  \
            av[m_], bv[n_], acc[m_][n_], 0, 0, 0);                              \
    __builtin_amdgcn_s_setprio(0);                                              \
    asm volatile("" ::: "memory");                                              \
  } while (0)

#pragma unroll 1
    for (int i = 0; i < NTILE / 2; ++i) {
      const int t1 = 2 * i + 1;
      const int t2 = (2 * i + 2 < NTILE) ? 2 * i + 2 : NTILE - 1;
      PHASE(0, 0, STGH(t1, 0, 16384));
      PHASE(0, 1, STGH(t1, 1, 16384));
      PHASE(1, 0, STGH(t2, 0, 0));
      PHASE(1, 1, STGH(t2, 1, 0));
    }
#undef PHASE
#undef STGH

#pragma unroll
    for (int n = 0; n < 2; ++n) {
      const int col = bn + wc * 32 + n * 16 + lr;
#pragma unroll
      for (int m = 0; m < 4; ++m) {
        const int row0 = bm + wr * 64 + m * 16 + kg * 4;
#pragma unroll
        for (int q = 0; q < 4; ++q)
          Cz[(long)(row0 + q) * HID + col] = acc[m][n][q];
      }
    }
  }
}

// ---------- causal row softmax: bf16 scores -> bf16 P (kend 128-aligned) ----------

__global__ __launch_bounds__(256)
void softmax_causal(const u16* __restrict__ Sc, u16* __restrict__ P, long sS, long sP)
{
  const int row  = blockIdx.x;
  const int z    = blockIdx.y;
  const int kend = ((row >> 7) + 1) << 7;
  const u16* srow = Sc + (long)z * sS + (long)row * S_LEN;
  u16*      prow = P  + (long)z * sP + (long)row * S_LEN;
  const int t = threadIdx.x;
  const int lane = t & 63, wave = t >> 6;

  const bool p0 = (8 * t) < kend;

  float e[8];
  float mx = -1e30f;
  if (p0) {
    uint4 u = reinterpret_cast<const uint4*>(srow)[t];
    uint32_t wv[4] = {u.x, u.y, u.z, u.w};
#pragma unroll
    for (int i = 0; i < 4; ++i) {
      const float lo = bf2f((wv[i] & 0xffffu) << 16);
      const float hi = bf2f(wv[i] & 0xffff0000u);
      e[2 * i]     = lo;
      e[2 * i + 1] = hi;
      mx = fmaxf(mx, fmaxf(lo, hi));
    }
  }

  __shared__ float red[8];
#pragma unroll
  for (int off = 32; off; off >>= 1) mx = fmaxf(mx, __shfl_down(mx, off));
  if (lane == 0) red[wave] = mx;
  __syncthreads();
  mx = fmaxf(fmaxf(red[0], red[1]), fmaxf(red[2], red[3]));

  float sm = 0.0f;
  if (p0) {
#pragma unroll
    for (int i = 0; i < 8; ++i) e[i] = __expf(e[i] - mx);
    sm = ((e[0] + e[1]) + (e[2] + e[3])) + ((e[4] + e[5]) + (e[6] + e[7]));
  }
#pragma unroll
  for (int off = 32; off; off >>= 1) sm += __shfl_down(sm, off);
  if (lane == 0) red[4 + wave] = sm;
  __syncthreads();
  sm = (red[4] + red[5]) + (red[6] + red[7]);

  const float inv = 1.0f / sm;
  if (p0) {
    uint32_t o[4];
#pragma unroll
    for (int i = 0; i < 4; ++i) {
      const uint32_t a = f2bf(e[2 * i] * inv);
      const uint32_t b = f2bf(e[2 * i + 1] * inv);
      o[i] = a | (b << 16);
    }
    reinterpret_cast<uint4*>(prow)[t] = make_uint4(o[0], o[1], o[2], o[3]);
  }
}

// ---------- launch ----------

extern "C" void kernel_launch(void* const* d_in, const int* in_sizes, int n_in,
                              void* d_out, int out_size, void* d_ws, size_t ws_size,
                              hipStream_t stream)
{
  const float* x  = (const float*)d_in[0];
  const float* Wq = (const float*)d_in[1];
  const float* bq = (const float*)d_in[2];
  const float* Wk = (const float*)d_in[3];
  const float* bk = (const float*)d_in[4];
  const float* Wv = (const float*)d_in[5];
  const float* bv = (const float*)d_in[6];
  float* out = (float*)d_out;

  const long M = (long)NB * S_LEN;  // 8192

  u16* xb  = (u16*)d_ws;
  u16* wqb = xb  + M * EMB;         // wq/wk/wv contiguous -> fused [3072,1024]
  u16* Qb  = wqb + 3L * HID * EMB;  // Q then K contiguous
  u16* Kb  = Qb  + M * HID;
  u16* VT  = Kb  + M * HID;
  char* rest = (char*)(VT + M * HID);
  const size_t used  = (size_t)(rest - (char*)d_ws);
  const size_t ssz   = (size_t)S_LEN * S_LEN;
  const size_t need4 = used + (size_t)NB * ssz * 2 * 2;   // bf16 scores + bf16 P
  const int nb = (ws_size >= need4) ? NB : 1;
  u16* scores = (u16*)rest;
  u16* P      = scores + (size_t)nb * ssz;

  // fp32 -> bf16 (single fused launch; nw4 = 1024*1024/4 = 2^18)
  cvt_all<<<2048, 256, 0, stream>>>(x, Wq, Wk, Wv, xb, wqb, (int)(M * EMB / 4), 18);

  // fused QKV projection: continuous-ring, 3 tiles/block, grid 256 = 1/CU
  gemm_proj8<<<256, 512, 0, stream>>>(xb, wqb, Qb, bq, bk, bv, VT);

  const float scale = 0.03125f;  // 1/sqrt(1024)
  const int TRI = 16 * 17 / 2;   // 136 lower-tri 128x128 blocks

  if (nb == NB) {
    dim3 gs(TRI, 1, NB);
    gemmT<<<gs, 256, 0, stream>>>(Qb, Kb, scores,
                                  S_LEN, (long)S_LEN * HID, (long)S_LEN * HID,
                                  (long)ssz, scale);
    softmax_causal<<<dim3(S_LEN, NB), 256, 0, stream>>>(scores, P, (long)ssz, (long)ssz);
    gemm_pv<<<dim3(8, 8, NB), 512, 0, stream>>>(P, VT, out);
  } else {
    for (int b = 0; b < NB; ++b) {
      const u16* Qbb = Qb + (long)b * S_LEN * HID;
      const u16* Kbb = Kb + (long)b * S_LEN * HID;
      const u16* VTb = VT + (long)b * HID * S_LEN;
      float* outb = out + (long)b * S_LEN * HID;
      dim3 gs(TRI, 1, 1);
      gemmT<<<gs, 256, 0, stream>>>(Qbb, Kbb, scores, S_LEN, 0, 0, 0, scale);
      softmax_causal<<<dim3(S_LEN, 1), 256, 0, stream>>>(scores, P, 0, 0);
      gemm_pv<<<dim3(8, 8, 1), 512, 0, stream>>>(P, VTb, outb);
    }
  }
}

// Round 18
// 152.930 us; speedup vs baseline: 1.0488x; 1.0009x over previous
//
#include <hip/hip_runtime.h>
#include <cstdint>
#include <cstddef>
#include <math.h>

typedef unsigned short u16;

#define S_LEN 2048
#define EMB   1024
#define HID   1024
#define NB    4

using bf16x8 = __attribute__((ext_vector_type(8))) __bf16;
using f32x4  = __attribute__((ext_vector_type(4))) float;

// ---------- helpers ----------

__device__ __forceinline__ u16 f2bf(float f) {
  union { float f; uint32_t u; } c; c.f = f;
  uint32_t u = c.u;
  uint32_t r = (u + 0x7fffu + ((u >> 16) & 1u)) >> 16;  // RNE
  return (u16)r;
}

__device__ __forceinline__ float bf2f(uint32_t hi16) {
  union { uint32_t u; float f; } c; c.u = hi16;
  return c.f;
}

__device__ __forceinline__ void gld_lds16(const u16* g, u16* l) {
  auto gp = (const __attribute__((address_space(1))) uint32_t*)(uintptr_t)(const void*)g;
  auto lp = (__attribute__((address_space(3))) uint32_t*)(uintptr_t)(void*)l;
  __builtin_amdgcn_global_load_lds(gp, lp, 16, 0, 0);
}

// ---------- fp32 -> bf16 convert: single fused launch ----------

__global__ void cvt_all(const float* __restrict__ x,  const float* __restrict__ wq,
                        const float* __restrict__ wk, const float* __restrict__ wv,
                        u16* __restrict__ xb, u16* __restrict__ wb, int nx4, int nw4lg2) {
  const int nw4 = 1 << nw4lg2;
  const int total = nx4 + 3 * nw4;
  int i = blockIdx.x * blockDim.x + threadIdx.x;
  const int stride = gridDim.x * blockDim.x;
  for (; i < total; i += stride) {
    const float* src; u16* dst; int j;
    if (i < nx4) { src = x; dst = xb; j = i; }
    else {
      const int k = i - nx4;
      const int wsel = k >> nw4lg2;
      j = k & (nw4 - 1);
      src = (wsel == 0) ? wq : (wsel == 1) ? wk : wv;
      dst = wb + ((size_t)wsel << (nw4lg2 + 2));
    }
    float4 v = reinterpret_cast<const float4*>(src)[j];
    reinterpret_cast<ushort4*>(dst)[j] =
      make_ushort4(f2bf(v.x), f2bf(v.y), f2bf(v.z), f2bf(v.w));
  }
}

// ============================================================================
// gemm_proj8: fused QKV projection, continuous 4-region ring across 3 tiles
// (R17-proven) + CROSS-PHASE REGISTER FILL/CONSUME (R14-proven transform):
//   phase p: { stage [half p+2 of tile t | half p-30 of tile t+1 | none];
//              vmcnt(3) [vmcnt(0) at t==2,p>=30]; barrier;
//              setprio; 16 MFMA <- set filled at p-1; setprio;
//              8 ds_read -> set for p+1 from region (p+1)&3 }
// Fill-safety: region (p+1)&3 holds half gp+1, staged at gp-1; this phase's
// vmcnt(3) (outstanding 6->3) drains exactly gp-1's loads, then barrier ->
// every wave confirmed before any wave's fill-read. Fill lgkm drains during
// the NEXT phase's stage+vmcnt+barrier (off the MFMA critical path).
// WAR: region filled-from at p is restaged at p+3 (barriers at p+1, p+2
// between). Tile boundary: p=31's fill reads half 0 of tile t+1 (staged at
// p=30, confirmed at p=31). t==2 tail fill = dummy read (values unused).
// E/O named register sets, 2 phases per iteration (rule #20).
// Tile 128x256, K=1024; 512 thr = 8 waves (2Mx4N, 64x64, acc[4][4]); 96 KB
// LDS; grid 256 = 1 block/CU exact; epilogue: QKV routing + bias.
// Involution chunk swizzle (0-conflict proven): chunk ^= row-bit3<<1.
// ============================================================================

__global__ __launch_bounds__(512, 1)
void gemm_proj8(const u16* __restrict__ A, const u16* __restrict__ Bw, u16* __restrict__ QK,
                const float* __restrict__ b0, const float* __restrict__ b1,
                const float* __restrict__ b2, u16* __restrict__ VT)
{
  constexpr int K  = 1024;
  constexpr long M = (long)NB * S_LEN;  // 8192

  __shared__ __align__(16) u16 smem[49152];   // 96 KB: 4 regions x 12288 u16

  const int tid = threadIdx.x;
  const int l   = tid & 63;
  const int w   = tid >> 6;            // 0..7
  const int wr  = w >> 2;              // 0..1 (64-row)
  const int wc  = w & 3;               // 0..3 (64-col)

  // fragment ds_read offsets (region-local, u16 units), swizzled
  const int lr  = l & 15;
  const int kg  = l >> 4;
  const int kgp = kg ^ (((lr >> 3) & 1) << 1);
  int aoff[4], boff[4];
#pragma unroll
  for (int m = 0; m < 4; ++m) aoff[m] = (wr * 64 + m * 16 + lr) * 32 + kgp * 8;
#pragma unroll
  for (int n = 0; n < 4; ++n) boff[n] = 4096 + (wc * 64 + n * 16 + lr) * 32 + kgp * 8;

  // staging lane geometry: row = tid>>2 (0..127), chunk = (tid&3) ^ row-bit3 flip
  const int srow = tid >> 2;
  const int acs  = (tid & 3) ^ (((tid >> 5) & 1) << 1);

  // per-tile geometry (compile-time indexed via unrolled outer loop)
  int bms[3], bns[3];
  const u16 *bA[3], *bB[3], *bB2[3];
#pragma unroll
  for (int t = 0; t < 3; ++t) {
    const int g = blockIdx.x + t * 256;      // 0..767
    bms[t] = (g & 63) * 128;
    bns[t] = (g >> 6) * 256;
    bA[t]  = A  + (long)(bms[t] + srow) * K + acs * 8;
    bB[t]  = Bw + (long)(bns[t] + srow) * K + acs * 8;
    bB2[t] = bB[t] + 128L * K;
  }

  // stage K-half h of tile tt into region rb (u16 offset)
#define STGH(tt, h, rb)                                                         \
  do {                                                                          \
    const long _o = (long)(h) * 32;                                             \
    gld_lds16(bA[tt]  + _o, smem + (rb) +        w * 512);                      \
    gld_lds16(bB[tt]  + _o, smem + (rb) + 4096 + w * 512);                      \
    gld_lds16(bB2[tt] + _o, smem + (rb) + 8192 + w * 512);                      \
  } while (0)

  // ---- single prologue: halves 0,1 of tile 0 -> regions 0,1 ----
  STGH(0, 0, 0);
  STGH(0, 1, 12288);
  asm volatile("s_waitcnt vmcnt(3)" ::: "memory");   // half 0 landed
  __builtin_amdgcn_s_barrier();
  asm volatile("" ::: "memory");

  bf16x8 Ea[4], Eb[4], Oa[4], Ob[4];
#pragma unroll
  for (int m_ = 0; m_ < 4; ++m_)
    Ea[m_] = *reinterpret_cast<const bf16x8*>(smem + aoff[m_]);
#pragma unroll
  for (int n_ = 0; n_ < 4; ++n_)
    Eb[n_] = *reinterpret_cast<const bf16x8*>(smem + boff[n_]);

// PHASEF: stage(p); vmcnt; barrier; MFMA(Ca,Cb); fill Fa,Fb <- region (p+1)&3
#define PHASEF(p, Fa, Fb, Ca, Cb)                                               \
  do {                                                                          \
    const int _p  = (p);                                                        \
    const int _rb = ((_p + 2) & 3) * 12288;                                     \
    if (_p < 30) {                                                              \
      STGH(t, _p + 2, _rb);                                                     \
      asm volatile("s_waitcnt vmcnt(3)" ::: "memory");                          \
    } else if (t < 2) {                                                         \
      STGH(t + 1, _p - 30, _rb);                                                \
      asm volatile("s_waitcnt vmcnt(3)" ::: "memory");                          \
    } else {                                                                    \
      asm volatile("s_waitcnt vmcnt(0)" ::: "memory");                          \
    }                                                                           \
    __builtin_amdgcn_s_barrier();                                               \
    asm volatile("" ::: "memory");                                              \
    __builtin_amdgcn_s_setprio(1);                                              \
    _Pragma("unroll")                                                           \
    for (int m_ = 0; m_ < 4; ++m_)                                              \
      _Pragma("unroll")                                                         \
      for (int n_ = 0; n_ < 4; ++n_)                                            \
        acc[m_][n_] = __builtin_amdgcn_mfma_f32_16x16x32_bf16(                  \
            Ca[m_], Cb[n_], acc[m_][n_], 0, 0, 0);                              \
    __builtin_amdgcn_s_setprio(0);                                              \
    asm volatile("" ::: "memory");                                              \
    {                                                                           \
      const u16* _hN = smem + ((_p + 1) & 3) * 12288;                           \
      _Pragma("unroll")                                                         \
      for (int m_ = 0; m_ < 4; ++m_)                                            \
        Fa[m_] = *reinterpret_cast<const bf16x8*>(_hN + aoff[m_]);              \
      _Pragma("unroll")                                                         \
      for (int n_ = 0; n_ < 4; ++n_)                                            \
        Fb[n_] = *reinterpret_cast<const bf16x8*>(_hN + boff[n_]);              \
    }                                                                           \
  } while (0)

#pragma unroll
  for (int t = 0; t < 3; ++t) {
    f32x4 acc[4][4] = {};

#pragma unroll 1
    for (int i = 0; i < 16; ++i) {
      PHASEF(2 * i,     Oa, Ob, Ea, Eb);   // even phase: consume E, fill O
      PHASEF(2 * i + 1, Ea, Eb, Oa, Ob);   // odd  phase: consume O, fill E
    }

    // ---- epilogue tile t (regs + global stores only; no LDS) ----
    const int bm = bms[t], bn = bns[t];
    const int sel = (bn + wc * 64) >> 10;   // 0=Q,1=K,2=V (wave-uniform)
    const float* bias = (sel == 0) ? b0 : (sel == 1) ? b1 : b2;
#pragma unroll
    for (int n = 0; n < 4; ++n) {
      const int col = bn + wc * 64 + n * 16 + lr;
      const int h   = col & (HID - 1);
      const float bbv = bias[h];
#pragma unroll
      for (int m = 0; m < 4; ++m) {
        const int row0 = bm + wr * 64 + m * 16 + kg * 4;
        if (sel < 2) {
          u16* dst = QK + (long)sel * M * HID + (long)row0 * HID + h;
#pragma unroll
          for (int q = 0; q < 4; ++q)
            dst[(long)q * HID] = f2bf(acc[m][n][q] + bbv);
        } else {
          const int b = row0 >> 11;
          const int s = row0 & (S_LEN - 1);
          ushort4 o = make_ushort4(f2bf(acc[m][n][0] + bbv), f2bf(acc[m][n][1] + bbv),
                                   f2bf(acc[m][n][2] + bbv), f2bf(acc[m][n][3] + bbv));
          *reinterpret_cast<ushort4*>(VT + ((long)b * HID + h) * S_LEN + s) = o;
        }
      }
    }
  }
#undef PHASEF
#undef STGH
}

// ============================================================================
// gemmT: scores GEMM (R13-proven, unchanged): 128x128, 256 thr, 4 waves,
// bf16 out + scale + causal mask, triangular grid + T1 swizzle.
// ============================================================================

__global__ __launch_bounds__(256, 2)
void gemmT(const u16* __restrict__ A, const u16* __restrict__ Bw, void* __restrict__ Cv,
           int N, long sA, long sB, long sC, float scale)
{
  constexpr int K = 1024;
  constexpr int NTILE = K / 64;        // 16
  const int z = blockIdx.z;
  A  += (long)z * sA;
  Bw += (long)z * sB;

  __shared__ __align__(16) u16 smem[32768];   // 64 KB

  const int tid = threadIdx.x;
  const int l   = tid & 63;
  const int w   = tid >> 6;            // 0..3
  const int wr  = w >> 1;              // 0..1
  const int wc  = w & 1;               // 0..1

  const int x0 = blockIdx.x;
  const int x  = (x0 & 7) * ((int)gridDim.x >> 3) + (x0 >> 3);
  int bi = (int)((sqrtf(8.0f * (float)x + 1.0f) - 1.0f) * 0.5f);
  while ((bi + 1) * (bi + 2) / 2 <= x) ++bi;
  while (bi * (bi + 1) / 2 > x) --bi;
  const int bm = bi * 128;
  const int bn = (x - bi * (bi + 1) / 2) * 128;

  const int arow = w * 16 + (l >> 2);                 // 0..63
  const int acs  = (l & 3) ^ (((l >> 5) & 1) << 1);
  const u16* gbA  = A  + (long)(bm + arow) * K + acs * 8;
  const u16* gbA2 = gbA + 64L * K;
  const u16* gbB  = Bw + (long)(bn + arow) * K + acs * 8;
  const u16* gbB2 = gbB + 64L * K;

#define STGH(t, s, dbase)                                                       \
  do {                                                                          \
    const long _o = (long)(t) * 64 + (s) * 32;                                  \
    gld_lds16(gbA  + _o, smem + (dbase) + (s) * 4096 +        w * 512);         \
    gld_lds16(gbA2 + _o, smem + (dbase) + (s) * 4096 + 2048 + w * 512);         \
    gld_lds16(gbB  + _o, smem + (dbase) + 8192 + (s) * 4096 +        w * 512);  \
    gld_lds16(gbB2 + _o, smem + (dbase) + 8192 + (s) * 4096 + 2048 + w * 512);  \
  } while (0)

  const int lr  = l & 15;
  const int kg  = l >> 4;
  const int kgp = kg ^ (((lr >> 3) & 1) << 1);
  int aoff[4], boff[4];
#pragma unroll
  for (int m = 0; m < 4; ++m) aoff[m] = (wr * 64 + m * 16 + lr) * 32 + kgp * 8;
#pragma unroll
  for (int n = 0; n < 4; ++n) boff[n] = (wc * 64 + n * 16 + lr) * 32 + kgp * 8;

  f32x4 acc[4][4] = {};

  STGH(0, 0, 0);
  STGH(0, 1, 0);
  asm volatile("s_waitcnt vmcnt(0)" ::: "memory");
  __builtin_amdgcn_s_barrier();
  asm volatile("" ::: "memory");

#define PHASE(d, s, STGSTMT)                                                    \
  do {                                                                          \
    const u16* hA = smem + (d) * 16384 + (s) * 4096;                            \
    const u16* hB = smem + (d) * 16384 + 8192 + (s) * 4096;                     \
    bf16x8 av[4], bv[4];                                                        \
    _Pragma("unroll")                                                           \
    for (int m_ = 0; m_ < 4; ++m_)                                              \
      av[m_] = *reinterpret_cast<const bf16x8*>(hA + aoff[m_]);                 \
    _Pragma("unroll")                                                           \
    for (int n_ = 0; n_ < 4; ++n_)                                              \
      bv[n_] = *reinterpret_cast<const bf16x8*>(hB + boff[n_]);                 \
    STGSTMT;                                                                    \
    asm volatile("s_waitcnt vmcnt(4)" ::: "memory");                            \
    __builtin_amdgcn_s_barrier();                                               \
    asm volatile("" ::: "memory");                                              \
    __builtin_amdgcn_s_setprio(1);                                              \
    _Pragma("unroll")                                                           \
    for (int m_ = 0; m_ < 4; ++m_)                                              \
      _Pragma("unroll")                                                         \
      for (int n_ = 0; n_ < 4; ++n_)                                            \
        acc[m_][n_] = __builtin_amdgcn_mfma_f32_16x16x32_bf16(                  \
            av[m_], bv[n_], acc[m_][n_], 0, 0, 0);                              \
    __builtin_amdgcn_s_setprio(0);                                              \
    asm volatile("" ::: "memory");                                              \
  } while (0)

#pragma unroll 1
  for (int i = 0; i < NTILE / 2; ++i) {
    const int t1 = 2 * i + 1;
    const int t2 = (2 * i + 2 < NTILE) ? 2 * i + 2 : NTILE - 1;
    PHASE(0, 0, STGH(t1, 0, 16384));
    PHASE(0, 1, STGH(t1, 1, 16384));
    PHASE(1, 0, STGH(t2, 0, 0));
    PHASE(1, 1, STGH(t2, 1, 0));
  }
#undef PHASE
#undef STGH

  u16* C = (u16*)Cv + (long)z * sC;
#pragma unroll
  for (int n = 0; n < 4; ++n) {
    const int col = bn + wc * 64 + n * 16 + lr;
#pragma unroll
    for (int m = 0; m < 4; ++m) {
      const int row0 = bm + wr * 64 + m * 16 + kg * 4;
#pragma unroll
      for (int q = 0; q < 4; ++q) {
        const int row = row0 + q;
        float v = acc[m][n][q] * scale;
        if (col > row) v = -1e30f;
        C[(long)row * N + col] = f2bf(v);
      }
    }
  }
}

// ============================================================================
// gemm_pv: load-balanced causal PV (R10-proven, unchanged).
// ============================================================================

__global__ __launch_bounds__(512, 2)
void gemm_pv(const u16* __restrict__ Pm, const u16* __restrict__ VTm, float* __restrict__ Cm)
{
  const int z = blockIdx.z;
  const u16* A = Pm  + (long)z * S_LEN * S_LEN;
  const u16* B = VTm + (long)z * HID * S_LEN;
  float*    Cz = Cm  + (long)z * S_LEN * HID;

  __shared__ __align__(16) u16 smem[32768];   // 64 KB

  const int tid = threadIdx.x;
  const int l   = tid & 63;
  const int w   = tid >> 6;
  const int wr  = w >> 2;              // 0..1 (64-row)
  const int wc  = w & 3;               // 0..3 (32-col)
  const int bn  = blockIdx.x * 128;
  const int pr  = blockIdx.y;          // 0..7

  const int lr  = l & 15;
  const int kg  = l >> 4;
  const int kgp = kg ^ (((lr >> 3) & 1) << 1);
  int aoff[4], boff[2];
#pragma unroll
  for (int m = 0; m < 4; ++m) aoff[m] = (wr * 64 + m * 16 + lr) * 32 + kgp * 8;
#pragma unroll
  for (int n = 0; n < 2; ++n) boff[n] = (wc * 32 + n * 16 + lr) * 32 + kgp * 8;

  const int arow = w * 16 + (l >> 2);                 // 0..127
  const int acs  = (l & 3) ^ (((l >> 5) & 1) << 1);

#pragma unroll 1
  for (int it = 0; it < 2; ++it) {
    const int bi = (it == 0) ? (15 - pr) : pr;        // long row-tile first
    const int bm = bi * 128;
    const int NTILE = (bi + 1) * 2;                   // even, >= 2

    const u16* gbA = A + (long)(bm + arow) * S_LEN + acs * 8;
    const u16* gbB = B + (long)(bn + arow) * S_LEN + acs * 8;

#define STGH(t, s, dbase)                                                       \
  do {                                                                          \
    const long _o = (long)(t) * 64 + (s) * 32;                                  \
    gld_lds16(gbA + _o, smem + (dbase) + (s) * 4096 + w * 512);                 \
    gld_lds16(gbB + _o, smem + (dbase) + 8192 + (s) * 4096 + w * 512);          \
  } while (0)

    if (it) {
      __builtin_amdgcn_s_barrier();
      asm volatile("" ::: "memory");
    }

    f32x4 acc[4][2] = {};

    STGH(0, 0, 0);
    STGH(0, 1, 0);
    asm volatile("s_waitcnt vmcnt(0)" ::: "memory");
    __builtin_amdgcn_s_barrier();
    asm volatile("" ::: "memory");

#define PHASE(d, s, STGSTMT)                                                    \
  do {                                                                          \
    const u16* hA = smem + (d) * 16384 + (s) * 4096;                            \
    const u16* hB = smem + (d) * 16384 + 8192 + (s) * 4096;                     \
    bf16x8 av[4], bv[2];                                                        \
    _Pragma("unroll")                                                           \
    for (int m_ = 0; m_ < 4; ++m_)                                              \
      av[m_] = *reinterpret_cast<const bf16x8*>(hA + aoff[m_]);                 \
    _Pragma("unroll")                                                           \
    for (int n_ = 0; n_ < 2; ++n_)                                              \
      bv[n_] = *reinterpret_cast<const bf16x8*>(hB + boff[n_]);                 \
    STGSTMT;                                                                    \
    asm volatile("s_waitcnt vmcnt(2)" ::: "memory");                            \
    __builtin_amdgcn_s_barrier();                                               \
    asm volatile("" ::: "memory");                                              \
    __builtin_amdgcn_s_setprio(1);                                              \
    _Pragma("unroll")                                                           \
    for (int m_ = 0; m_ < 4; ++m_)                                              \
      _Pragma("unroll")                                                         \
      for (int n_ = 0; n_ < 2; ++n_)                                            \
        acc[m_][n_] = __builtin_amdgcn_mfma_f32_16x16x32_bf16(                  \
            av[m_], bv[n_], acc[m_][n_], 0, 0, 0);                              \
    __builtin_amdgcn_s_setprio(0);                                              \
    asm volatile("" ::: "memory");                                              \
  } while (0)

#pragma unroll 1
    for (int i = 0; i < NTILE / 2; ++i) {
      const int t1 = 2 * i + 1;
      const int t2 = (2 * i + 2 < NTILE) ? 2 * i + 2 : NTILE - 1;
      PHASE(0, 0, STGH(t1, 0, 16384));
      PHASE(0, 1, STGH(t1, 1, 16384));
      PHASE(1, 0, STGH(t2, 0, 0));
      PHASE(1, 1, STGH(t2, 1, 0));
    }
#undef PHASE
#undef STGH

#pragma unroll
    for (int n = 0; n < 2; ++n) {
      const int col = bn + wc * 32 + n * 16 + lr;
#pragma unroll
      for (int m = 0; m < 4; ++m) {
        const int row0 = bm + wr * 64 + m * 16 + kg * 4;
#pragma unroll
        for (int q = 0; q < 4; ++q)
          Cz[(long)(row0 + q) * HID + col] = acc[m][n][q];
      }
    }
  }
}

// ---------- causal row softmax: bf16 scores -> bf16 P (kend 128-aligned) ----------

__global__ __launch_bounds__(256)
void softmax_causal(const u16* __restrict__ Sc, u16* __restrict__ P, long sS, long sP)
{
  const int row  = blockIdx.x;
  const int z    = blockIdx.y;
  const int kend = ((row >> 7) + 1) << 7;
  const u16* srow = Sc + (long)z * sS + (long)row * S_LEN;
  u16*      prow = P  + (long)z * sP + (long)row * S_LEN;
  const int t = threadIdx.x;
  const int lane = t & 63, wave = t >> 6;

  const bool p0 = (8 * t) < kend;

  float e[8];
  float mx = -1e30f;
  if (p0) {
    uint4 u = reinterpret_cast<const uint4*>(srow)[t];
    uint32_t wv[4] = {u.x, u.y, u.z, u.w};
#pragma unroll
    for (int i = 0; i < 4; ++i) {
      const float lo = bf2f((wv[i] & 0xffffu) << 16);
      const float hi = bf2f(wv[i] & 0xffff0000u);
      e[2 * i]     = lo;
      e[2 * i + 1] = hi;
      mx = fmaxf(mx, fmaxf(lo, hi));
    }
  }

  __shared__ float red[8];
#pragma unroll
  for (int off = 32; off; off >>= 1) mx = fmaxf(mx, __shfl_down(mx, off));
  if (lane == 0) red[wave] = mx;
  __syncthreads();
  mx = fmaxf(fmaxf(red[0], red[1]), fmaxf(red[2], red[3]));

  float sm = 0.0f;
  if (p0) {
#pragma unroll
    for (int i = 0; i < 8; ++i) e[i] = __expf(e[i] - mx);
    sm = ((e[0] + e[1]) + (e[2] + e[3])) + ((e[4] + e[5]) + (e[6] + e[7]));
  }
#pragma unroll
  for (int off = 32; off; off >>= 1) sm += __shfl_down(sm, off);
  if (lane == 0) red[4 + wave] = sm;
  __syncthreads();
  sm = (red[4] + red[5]) + (red[6] + red[7]);

  const float inv = 1.0f / sm;
  if (p0) {
    uint32_t o[4];
#pragma unroll
    for (int i = 0; i < 4; ++i) {
      const uint32_t a = f2bf(e[2 * i] * inv);
      const uint32_t b = f2bf(e[2 * i + 1] * inv);
      o[i] = a | (b << 16);
    }
    reinterpret_cast<uint4*>(prow)[t] = make_uint4(o[0], o[1], o[2], o[3]);
  }
}

// ---------- launch ----------

extern "C" void kernel_launch(void* const* d_in, const int* in_sizes, int n_in,
                              void* d_out, int out_size, void* d_ws, size_t ws_size,
                              hipStream_t stream)
{
  const float* x  = (const float*)d_in[0];
  const float* Wq = (const float*)d_in[1];
  const float* bq = (const float*)d_in[2];
  const float* Wk = (const float*)d_in[3];
  const float* bk = (const float*)d_in[4];
  const float* Wv = (const float*)d_in[5];
  const float* bv = (const float*)d_in[6];
  float* out = (float*)d_out;

  const long M = (long)NB * S_LEN;  // 8192

  u16* xb  = (u16*)d_ws;
  u16* wqb = xb  + M * EMB;         // wq/wk/wv contiguous -> fused [3072,1024]
  u16* Qb  = wqb + 3L * HID * EMB;  // Q then K contiguous
  u16* Kb  = Qb  + M * HID;
  u16* VT  = Kb  + M * HID;
  char* rest = (char*)(VT + M * HID);
  const size_t used  = (size_t)(rest - (char*)d_ws);
  const size_t ssz   = (size_t)S_LEN * S_LEN;
  const size_t need4 = used + (size_t)NB * ssz * 2 * 2;   // bf16 scores + bf16 P
  const int nb = (ws_size >= need4) ? NB : 1;
  u16* scores = (u16*)rest;
  u16* P      = scores + (size_t)nb * ssz;

  // fp32 -> bf16 (single fused launch; nw4 = 1024*1024/4 = 2^18)
  cvt_all<<<2048, 256, 0, stream>>>(x, Wq, Wk, Wv, xb, wqb, (int)(M * EMB / 4), 18);

  // fused QKV projection: continuous-ring + fill/consume, grid 256 = 1/CU
  gemm_proj8<<<256, 512, 0, stream>>>(xb, wqb, Qb, bq, bk, bv, VT);

  const float scale = 0.03125f;  // 1/sqrt(1024)
  const int TRI = 16 * 17 / 2;   // 136 lower-tri 128x128 blocks

  if (nb == NB) {
    dim3 gs(TRI, 1, NB);
    gemmT<<<gs, 256, 0, stream>>>(Qb, Kb, scores,
                                  S_LEN, (long)S_LEN * HID, (long)S_LEN * HID,
                                  (long)ssz, scale);
    softmax_causal<<<dim3(S_LEN, NB), 256, 0, stream>>>(scores, P, (long)ssz, (long)ssz);
    gemm_pv<<<dim3(8, 8, NB), 512, 0, stream>>>(P, VT, out);
  } else {
    for (int b = 0; b < NB; ++b) {
      const u16* Qbb = Qb + (long)b * S_LEN * HID;
      const u16* Kbb = Kb + (long)b * S_LEN * HID;
      const u16* VTb = VT + (long)b * HID * S_LEN;
      float* outb = out + (long)b * S_LEN * HID;
      dim3 gs(TRI, 1, 1);
      gemmT<<<gs, 256, 0, stream>>>(Qbb, Kbb, scores, S_LEN, 0, 0, 0, scale);
      softmax_causal<<<dim3(S_LEN, 1), 256, 0, stream>>>(scores, P, 0, 0);
      gemm_pv<<<dim3(8, 8, 1), 512, 0, stream>>>(P, VTb, outb);
    }
  }
}